// Round 4
// baseline (237.773 us; speedup 1.0000x reference)
//
#include <hip/hip_runtime.h>
#include <hip/hip_cooperative_groups.h>
#include <math.h>

namespace cg = cooperative_groups;

// Problem constants: b=2, h=4, n_tot=585, d=128, n=512, k=8
// Levels: L0 rows [0,512), L1 [512,576), L2 [576,584), L3 {584}
// Lane layout: s = lane>>3 (key slot 0..7), c = lane&7 (dim chunk of 16)
#define D 128
#define NTOT 585
#define SCALE 0.08838834764831845f  // 1/sqrt(128)
#define THIRD 0.33333333333333333f
#define LROW 132                    // 128 + 4 pad

__device__ __forceinline__ float rsum_c(float v) {  // sum over c (strides 1,2,4)
    v += __shfl_xor(v, 1, 64);
    v += __shfl_xor(v, 2, 64);
    v += __shfl_xor(v, 4, 64);
    return v;
}
__device__ __forceinline__ float rsum_s(float v) {  // sum over s (strides 8,16,32)
    v += __shfl_xor(v, 8, 64);
    v += __shfl_xor(v, 16, 64);
    v += __shfl_xor(v, 32, 64);
    return v;
}
__device__ __forceinline__ float rmax_s(float v) {
    v = fmaxf(v, __shfl_xor(v, 8, 64));
    v = fmaxf(v, __shfl_xor(v, 16, 64));
    v = fmaxf(v, __shfl_xor(v, 32, 64));
    return v;
}

__device__ __forceinline__ float dot16(const float4 q[4], const float* __restrict__ row, int c) {
    const float4* k = (const float4*)(row + (c << 4));
    float4 k0 = k[0], k1 = k[1], k2 = k[2], k3 = k[3];
    float p0 = q[0].x * k0.x + q[0].y * k0.y + q[0].z * k0.z + q[0].w * k0.w;
    float p1 = q[1].x * k1.x + q[1].y * k1.y + q[1].z * k1.z + q[1].w * k1.w;
    float p2 = q[2].x * k2.x + q[2].y * k2.y + q[2].z * k2.z + q[2].w * k2.w;
    float p3 = q[3].x * k3.x + q[3].y * k3.y + q[3].z * k3.z + q[3].w * k3.w;
    return (p0 + p1) + (p2 + p3);
}

__device__ __forceinline__ void vacc(float w, const float* __restrict__ row, int c, float4 acc[4]) {
    const float4* v = (const float4*)(row + (c << 4));
#pragma unroll
    for (int u = 0; u < 4; ++u) {
        float4 t = v[u];
        acc[u].x += w * t.x; acc[u].y += w * t.y; acc[u].z += w * t.z; acc[u].w += w * t.w;
    }
}

__device__ __forceinline__ void attend(const float4 q[4], const float* __restrict__ krow,
                                       const float* __restrict__ vrow, int c, float4 acc[4]) {
    float lg = rsum_c(dot16(q, krow, c)) * SCALE;
    float m = rmax_s(lg);
    float e = __expf(lg - m);
    float z = rsum_s(e);
    vacc(e / z, vrow, c, acc);
}

__device__ __forceinline__ void loadq(const float* __restrict__ qrow, int c, float4 q[4]) {
    const float4* qp = (const float4*)(qrow + (c << 4));
#pragma unroll
    for (int u = 0; u < 4; ++u) q[u] = qp[u];
}

__device__ __forceinline__ void butterfly_acc(float4 acc[4]) {
#pragma unroll
    for (int u = 0; u < 4; ++u) {
        acc[u].x = rsum_s(acc[u].x);
        acc[u].y = rsum_s(acc[u].y);
        acc[u].z = rsum_s(acc[u].z);
        acc[u].w = rsum_s(acc[u].w);
    }
}

// One level-0 query: sib (global K/V) + anc (LDS K, global V), write Out row i.
__device__ __forceinline__ void l0_query(int i, int g, int s, int c,
                                         const float* __restrict__ Qb,
                                         const float* __restrict__ Kb,
                                         const float* __restrict__ Vb,
                                         const float* __restrict__ Ksh,
                                         float* __restrict__ Ob) {
    float4 q4[4];
    loadq(Qb + (size_t)i * D, c, q4);
    float4 acc[4] = {{0,0,0,0},{0,0,0,0},{0,0,0,0},{0,0,0,0}};
    // sib
    {
        const int r = 8 * g + s;
        const int idx = (r <= i) ? r : 0;
        attend(q4, Kb + (size_t)idx * D, Vb + (size_t)idx * D, c, acc);
    }
    // anc: 64 entries in 8 rounds; K from LDS
    {
        float lg[8];
        int vidx[8];
#pragma unroll
        for (int r = 0; r < 8; ++r) {
            const int j = 8 * r + s;
            const bool pass = (8 * (j + 1) <= i);
            vidx[r] = pass ? (512 + j) : 0;
            lg[r] = rsum_c(dot16(q4, &Ksh[(pass ? j : 64) * LROW], c)) * SCALE;
        }
        float m = lg[0];
#pragma unroll
        for (int r = 1; r < 8; ++r) m = fmaxf(m, lg[r]);
        m = rmax_s(m);
        float z = 0.f;
#pragma unroll
        for (int r = 0; r < 8; ++r) { lg[r] = __expf(lg[r] - m); z += lg[r]; }
        z = rsum_s(z);
        const float inv = 1.f / z;
#pragma unroll
        for (int r = 0; r < 8; ++r) vacc(lg[r] * inv, Vb + (size_t)vidx[r] * D, c, acc);
    }
    butterfly_acc(acc);
    if (s == 0) {
        float4* orow = (float4*)(Ob + (size_t)i * D + (c << 4));
#pragma unroll
        for (int u = 0; u < 4; ++u)
            orow[u] = make_float4(acc[u].x * THIRD, acc[u].y * THIRD,
                                  acc[u].z * THIRD, acc[u].w * THIRD);
    }
}

// =============== Fused cooperative kernel: 256 blocks x 512 threads ==========
// Co-residency needs only 1 block/CU: 8 waves, 34.3KB LDS, VGPR<=256 — safe.
// Block b: bh = b>>5, gb = b&31 (covers L0 groups 2gb, 2gb+1; L1 queries 2gb, 2gb+1).
__global__ __launch_bounds__(512) void sequoia_fused(const float* __restrict__ Q,
                                                     const float* __restrict__ K,
                                                     const float* __restrict__ V,
                                                     float* __restrict__ Out) {
    __shared__ float Ksh[65 * LROW];
    cg::grid_group grid = cg::this_grid();

    const int tid = threadIdx.x;
    const int wave = tid >> 6;
    const int lane = tid & 63;
    const int s = lane >> 3, c = lane & 7;
    const int bh = blockIdx.x >> 5;
    const int gb = blockIdx.x & 31;
    const float* Qb = Q + (size_t)bh * NTOT * D;
    const float* Kb = K + (size_t)bh * NTOT * D;
    const float* Vb = V + (size_t)bh * NTOT * D;
    float* Ob = Out + (size_t)bh * NTOT * D;

    // Stage anc K rows 512..575 -> Ksh rows 0..63; K row 0 -> Ksh row 64.
    for (int t = tid; t < 65 * 32; t += 512) {
        const int row = t >> 5, col = (t & 31) << 2;
        const int src = (row < 64) ? (512 + row) : 0;
        *(float4*)(&Ksh[row * LROW + col]) = *(const float4*)(Kb + (size_t)src * D + col);
    }
    __syncthreads();

    // ================= Phase 0: level 0, two queries per wave ================
#pragma unroll
    for (int qq = 0; qq < 2; ++qq) {
        const int g = 2 * gb + qq;
        l0_query(8 * g + wave, g, s, c, Qb, Kb, Vb, Ksh, Ob);
    }

    __threadfence();   // agent-scope release: L2 writeback for cross-XCD readers
    grid.sync();

    // ================= Phase 1: level 1, waves 0..1 per block ================
    if (wave < 2) {
        const int i = 2 * gb + wave;  // 0..63
        float4 q4[4];
        loadq(Qb + (size_t)(512 + i) * D, c, q4);
        float4 acc[4] = {{0,0,0,0},{0,0,0,0},{0,0,0,0},{0,0,0,0}};
        // sib: r<=i -> K LDS row r, V ORIGINAL 512+r; masked -> K LDS 64, V UPDATED row 0
        {
            const int r = 8 * (i >> 3) + s;
            const bool pass = (r <= i);
            const float* vrow = pass ? (Vb + (size_t)(512 + r) * D) : Ob;
            attend(q4, &Ksh[(pass ? r : 64) * LROW], vrow, c, acc);
        }
        // anc: pass iff 8(s+1)<=i -> K global 576+s, V original; masked -> K LDS 64, V updated row 0
        {
            const bool pass = (8 * (s + 1) <= i);
            const float* krow = pass ? (Kb + (size_t)(576 + s) * D) : &Ksh[64 * LROW];
            const float* vrow = pass ? (Vb + (size_t)(576 + s) * D) : Ob;
            attend(q4, krow, vrow, c, acc);
        }
        // chi: s==0 -> K global 8i, V UPDATED 8i; masked -> K LDS 64, V UPDATED row 0
        {
            const int idx = (s == 0) ? 8 * i : 0;
            const float* krow = (s == 0) ? (Kb + (size_t)idx * D) : &Ksh[64 * LROW];
            attend(q4, krow, Ob + (size_t)idx * D, c, acc);
        }
        butterfly_acc(acc);
        if (s == 0) {
            float4* orow = (float4*)(Ob + (size_t)(512 + i) * D + (c << 4));
#pragma unroll
            for (int u = 0; u < 4; ++u)
                orow[u] = make_float4(acc[u].x * THIRD, acc[u].y * THIRD,
                                      acc[u].z * THIRD, acc[u].w * THIRD);
        }
    }

    __threadfence();
    grid.sync();

    // ======== Phase 2+3: levels 2 and 3, blocks with gb==0 (one per bh) ======
    if (gb == 0) {
        const int i = wave;  // level-2 query 0..7
        float4 q4[4];
        loadq(Qb + (size_t)(576 + i) * D, c, q4);
        float4 acc[4] = {{0,0,0,0},{0,0,0,0},{0,0,0,0},{0,0,0,0}};
        // sib: pass iff s<=i -> K global 576+s, V original; masked -> K LDS 64, V updated row 0
        {
            const bool pass = (s <= i);
            const float* krow = pass ? (Kb + (size_t)(576 + s) * D) : &Ksh[64 * LROW];
            const float* vrow = pass ? (Vb + (size_t)(576 + s) * D) : Ob;
            attend(q4, krow, vrow, c, acc);
        }
        // chi: s==0 -> K LDS row 8i (== K row 512+8i), V UPDATED 512+8i; masked -> LDS 64 / updated 0
        {
            const int krow = (s == 0) ? 8 * i : 64;
            const float* vrow = Ob + (size_t)((s == 0) ? 512 + 8 * i : 0) * D;
            attend(q4, &Ksh[krow * LROW], vrow, c, acc);
        }
        butterfly_acc(acc);
        // anc: single always-masked entry -> weight exactly 1 on UPDATED row 0 (post-butterfly)
        float4 o23[4];
        {
            const float4* r0 = (const float4*)(Ob + (c << 4));
#pragma unroll
            for (int u = 0; u < 4; ++u) {
                float4 z = r0[u];
                o23[u] = make_float4((acc[u].x + z.x) * THIRD, (acc[u].y + z.y) * THIRD,
                                     (acc[u].z + z.z) * THIRD, (acc[u].w + z.w) * THIRD);
            }
        }
        if (s == 0) {
            float4* orow = (float4*)(Ob + (size_t)(576 + i) * D + (c << 4));
#pragma unroll
            for (int u = 0; u < 4; ++u) orow[u] = o23[u];
        }
        // ---- level 3 (wave 0): row 584; updated row 576 is o23 in registers ----
        if (wave == 0) {
            float4 q5[4];
            loadq(Qb + (size_t)584 * D, c, q5);
            const float* krow = (s == 0) ? (Kb + (size_t)576 * D) : &Ksh[64 * LROW];
            float lg = rsum_c(dot16(q5, krow, c)) * SCALE;
            float m = rmax_s(lg);
            float e = __expf(lg - m);
            float z = rsum_s(e);
            const float w = e / z;
            const float4* r0 = (const float4*)(Ob + (c << 4));
            float4 acc3[4];
#pragma unroll
            for (int u = 0; u < 4; ++u) {
                float4 vv = r0[u];
                if (s == 0) vv = o23[u];
                acc3[u] = make_float4(w * vv.x, w * vv.y, w * vv.z, w * vv.w);
            }
            butterfly_acc(acc3);
            // sib: 8 identical entries on row 584 -> contributes ORIGINAL V[584]
            if (s == 0) {
                const float4* v584 = (const float4*)(Vb + (size_t)584 * D + (c << 4));
                float4* orow = (float4*)(Ob + (size_t)584 * D + (c << 4));
#pragma unroll
                for (int u = 0; u < 4; ++u) {
                    float4 bb = v584[u];
                    orow[u] = make_float4((acc3[u].x + bb.x) * THIRD, (acc3[u].y + bb.y) * THIRD,
                                          (acc3[u].z + bb.z) * THIRD, (acc3[u].w + bb.w) * THIRD);
                }
            }
        }
    }
}

// =================== Fallback path: R2's proven 3-kernel version =============
__global__ __launch_bounds__(256) void level0_kernel(const float* __restrict__ Q,
                                                     const float* __restrict__ K,
                                                     const float* __restrict__ V,
                                                     float* __restrict__ Out) {
    const int gwave = (blockIdx.x * 256 + threadIdx.x) >> 6;
    const int lane = threadIdx.x & 63;
    const int s = lane >> 3, c = lane & 7;
    const int i = gwave & 511;
    const int bh = gwave >> 9;
    const float* Qb = Q + (size_t)bh * NTOT * D;
    const float* Kb = K + (size_t)bh * NTOT * D;
    const float* Vb = V + (size_t)bh * NTOT * D;
    float* Ob = Out + (size_t)bh * NTOT * D;

    float4 q4[4];
    loadq(Qb + (size_t)i * D, c, q4);
    float4 acc[4] = {{0,0,0,0},{0,0,0,0},{0,0,0,0},{0,0,0,0}};
    {
        const int r = (i & ~7) + s;
        const int idx = (r <= i) ? r : 0;
        attend(q4, Kb + (size_t)idx * D, Vb + (size_t)idx * D, c, acc);
    }
    {
        float lg[8];
        int idx[8];
#pragma unroll
        for (int r = 0; r < 8; ++r) {
            const int j = 8 * r + s;
            idx[r] = (8 * (j + 1) <= i) ? (512 + j) : 0;
            lg[r] = rsum_c(dot16(q4, Kb + (size_t)idx[r] * D, c)) * SCALE;
        }
        float m = lg[0];
#pragma unroll
        for (int r = 1; r < 8; ++r) m = fmaxf(m, lg[r]);
        m = rmax_s(m);
        float z = 0.f;
#pragma unroll
        for (int r = 0; r < 8; ++r) { lg[r] = __expf(lg[r] - m); z += lg[r]; }
        z = rsum_s(z);
        const float inv = 1.f / z;
#pragma unroll
        for (int r = 0; r < 8; ++r) vacc(lg[r] * inv, Vb + (size_t)idx[r] * D, c, acc);
    }
    butterfly_acc(acc);
    if (s == 0) {
        float4* orow = (float4*)(Ob + (size_t)i * D + (c << 4));
#pragma unroll
        for (int u = 0; u < 4; ++u)
            orow[u] = make_float4(acc[u].x * THIRD, acc[u].y * THIRD,
                                  acc[u].z * THIRD, acc[u].w * THIRD);
    }
}

__global__ __launch_bounds__(256) void level1_kernel(const float* __restrict__ Q,
                                                     const float* __restrict__ K,
                                                     const float* __restrict__ V,
                                                     float* __restrict__ Out) {
    const int gwave = (blockIdx.x * 256 + threadIdx.x) >> 6;
    const int lane = threadIdx.x & 63;
    const int s = lane >> 3, c = lane & 7;
    const int i = gwave & 63;
    const int bh = gwave >> 6;
    const float* Qb = Q + (size_t)bh * NTOT * D;
    const float* Kb = K + (size_t)bh * NTOT * D;
    const float* Vb = V + (size_t)bh * NTOT * D;
    float* Ob = Out + (size_t)bh * NTOT * D;

    float4 q4[4];
    loadq(Qb + (size_t)(512 + i) * D, c, q4);
    float4 acc[4] = {{0,0,0,0},{0,0,0,0},{0,0,0,0},{0,0,0,0}};
    {
        const int r = (i & ~7) + s;
        const bool pass = (r <= i);
        const float* krow = Kb + (size_t)(pass ? 512 + r : 0) * D;
        const float* vrow = pass ? (Vb + (size_t)(512 + r) * D) : Ob;
        attend(q4, krow, vrow, c, acc);
    }
    {
        const bool pass = (8 * (s + 1) <= i);
        const float* krow = Kb + (size_t)(pass ? 576 + s : 0) * D;
        const float* vrow = pass ? (Vb + (size_t)(576 + s) * D) : Ob;
        attend(q4, krow, vrow, c, acc);
    }
    {
        const int idx = (s == 0) ? 8 * i : 0;
        attend(q4, Kb + (size_t)idx * D, Ob + (size_t)idx * D, c, acc);
    }
    butterfly_acc(acc);
    if (s == 0) {
        float4* orow = (float4*)(Ob + (size_t)(512 + i) * D + (c << 4));
#pragma unroll
        for (int u = 0; u < 4; ++u)
            orow[u] = make_float4(acc[u].x * THIRD, acc[u].y * THIRD,
                                  acc[u].z * THIRD, acc[u].w * THIRD);
    }
}

__global__ __launch_bounds__(512) void levels23_kernel(const float* __restrict__ Q,
                                                       const float* __restrict__ K,
                                                       const float* __restrict__ V,
                                                       float* __restrict__ Out) {
    const int bh = blockIdx.x;
    const int wave = threadIdx.x >> 6;
    const int lane = threadIdx.x & 63;
    const int s = lane >> 3, c = lane & 7;
    const float* Qb = Q + (size_t)bh * NTOT * D;
    const float* Kb = K + (size_t)bh * NTOT * D;
    const float* Vb = V + (size_t)bh * NTOT * D;
    float* Ob = Out + (size_t)bh * NTOT * D;

    const int i = wave;
    float4 q4[4];
    loadq(Qb + (size_t)(576 + i) * D, c, q4);
    float4 acc[4] = {{0,0,0,0},{0,0,0,0},{0,0,0,0},{0,0,0,0}};
    {
        const bool pass = (s <= i);
        const float* krow = Kb + (size_t)(pass ? 576 + s : 0) * D;
        const float* vrow = pass ? (Vb + (size_t)(576 + s) * D) : Ob;
        attend(q4, krow, vrow, c, acc);
    }
    {
        const int idx = (s == 0) ? (512 + 8 * i) : 0;
        attend(q4, Kb + (size_t)idx * D, Ob + (size_t)idx * D, c, acc);
    }
    butterfly_acc(acc);
    float4 o23[4];
    {
        const float4* r0 = (const float4*)(Ob + (c << 4));
#pragma unroll
        for (int u = 0; u < 4; ++u) {
            float4 z = r0[u];
            o23[u] = make_float4((acc[u].x + z.x) * THIRD, (acc[u].y + z.y) * THIRD,
                                 (acc[u].z + z.z) * THIRD, (acc[u].w + z.w) * THIRD);
        }
    }
    if (s == 0) {
        float4* orow = (float4*)(Ob + (size_t)(576 + i) * D + (c << 4));
#pragma unroll
        for (int u = 0; u < 4; ++u) orow[u] = o23[u];
    }
    if (wave == 0) {
        float4 q5[4];
        loadq(Qb + (size_t)584 * D, c, q5);
        const float* krow = Kb + (size_t)((s == 0) ? 576 : 0) * D;
        float lg = rsum_c(dot16(q5, krow, c)) * SCALE;
        float m = rmax_s(lg);
        float e = __expf(lg - m);
        float z = rsum_s(e);
        const float w = e / z;
        const float4* r0 = (const float4*)(Ob + (c << 4));
        float4 acc3[4];
#pragma unroll
        for (int u = 0; u < 4; ++u) {
            float4 vv = r0[u];
            if (s == 0) vv = o23[u];
            acc3[u] = make_float4(w * vv.x, w * vv.y, w * vv.z, w * vv.w);
        }
        butterfly_acc(acc3);
        if (s == 0) {
            const float4* v584 = (const float4*)(Vb + (size_t)584 * D + (c << 4));
            float4* orow = (float4*)(Ob + (size_t)584 * D + (c << 4));
#pragma unroll
            for (int u = 0; u < 4; ++u) {
                float4 bb = v584[u];
                orow[u] = make_float4((acc3[u].x + bb.x) * THIRD, (acc3[u].y + bb.y) * THIRD,
                                      (acc3[u].z + bb.z) * THIRD, (acc3[u].w + bb.w) * THIRD);
            }
        }
    }
}

extern "C" void kernel_launch(void* const* d_in, const int* in_sizes, int n_in,
                              void* d_out, int out_size, void* d_ws, size_t ws_size,
                              hipStream_t stream) {
    const float* Q = (const float*)d_in[0];
    const float* K = (const float*)d_in[1];
    const float* V = (const float*)d_in[2];
    float* Out = (float*)d_out;
    void* args[] = {(void*)&Q, (void*)&K, (void*)&V, (void*)&Out};
    // 256 blocks x 512 threads: co-residency needs only 1 block/CU (8 waves,
    // 34.3KB LDS, VGPR budget 256 at 2 waves/SIMD) — cooperative-launch safe.
    hipError_t err = hipLaunchCooperativeKernel((void*)sequoia_fused, dim3(256),
                                                dim3(512), args, 0, stream);
    if (err != hipSuccess) {
        // Cooperative rejected (too large / unsupported / capture): clear the
        // error and run the proven 3-kernel path instead. Same work, same
        // output — deterministic per environment.
        (void)hipGetLastError();
        hipLaunchKernelGGL(level0_kernel, dim3(1024), dim3(256), 0, stream, Q, K, V, Out);
        hipLaunchKernelGGL(level1_kernel, dim3(128), dim3(256), 0, stream, Q, K, V, Out);
        hipLaunchKernelGGL(levels23_kernel, dim3(8), dim3(512), 0, stream, Q, K, V, Out);
    }
}

// Round 5
// 111.435 us; speedup vs baseline: 2.1337x; 2.1337x over previous
//
#include <hip/hip_runtime.h>
#include <math.h>

// Problem constants: b=2, h=4, n_tot=585, d=128, n=512, k=8
// Levels: L0 rows [0,512), L1 [512,576), L2 [576,584), L3 {584}
#define D 128
#define NTOT 585
#define SCALE 0.08838834764831845f  // 1/sqrt(128)
#define THIRD 0.33333333333333333f

// ======================= helpers for level1 / levels23 =======================
// (lane layout: s = lane>>3 key slot, c = lane&7 dim chunk of 16) — R2-proven.
__device__ __forceinline__ float rsum_c(float v) {
    v += __shfl_xor(v, 1, 64);
    v += __shfl_xor(v, 2, 64);
    v += __shfl_xor(v, 4, 64);
    return v;
}
__device__ __forceinline__ float rsum_s(float v) {
    v += __shfl_xor(v, 8, 64);
    v += __shfl_xor(v, 16, 64);
    v += __shfl_xor(v, 32, 64);
    return v;
}
__device__ __forceinline__ float rmax_s(float v) {
    v = fmaxf(v, __shfl_xor(v, 8, 64));
    v = fmaxf(v, __shfl_xor(v, 16, 64));
    v = fmaxf(v, __shfl_xor(v, 32, 64));
    return v;
}
__device__ __forceinline__ float dot16(const float4 q[4], const float* __restrict__ row, int c) {
    const float4* k = (const float4*)(row + (c << 4));
    float4 k0 = k[0], k1 = k[1], k2 = k[2], k3 = k[3];
    float p0 = q[0].x * k0.x + q[0].y * k0.y + q[0].z * k0.z + q[0].w * k0.w;
    float p1 = q[1].x * k1.x + q[1].y * k1.y + q[1].z * k1.z + q[1].w * k1.w;
    float p2 = q[2].x * k2.x + q[2].y * k2.y + q[2].z * k2.z + q[2].w * k2.w;
    float p3 = q[3].x * k3.x + q[3].y * k3.y + q[3].z * k3.z + q[3].w * k3.w;
    return (p0 + p1) + (p2 + p3);
}
__device__ __forceinline__ void vacc(float w, const float* __restrict__ row, int c, float4 acc[4]) {
    const float4* v = (const float4*)(row + (c << 4));
#pragma unroll
    for (int u = 0; u < 4; ++u) {
        float4 t = v[u];
        acc[u].x += w * t.x; acc[u].y += w * t.y; acc[u].z += w * t.z; acc[u].w += w * t.w;
    }
}
__device__ __forceinline__ void attend(const float4 q[4], const float* __restrict__ krow,
                                       const float* __restrict__ vrow, int c, float4 acc[4]) {
    float lg = rsum_c(dot16(q, krow, c)) * SCALE;
    float m = rmax_s(lg);
    float e = __expf(lg - m);
    float z = rsum_s(e);
    vacc(e / z, vrow, c, acc);
}
__device__ __forceinline__ void loadq(const float* __restrict__ qrow, int c, float4 q[4]) {
    const float4* qp = (const float4*)(qrow + (c << 4));
#pragma unroll
    for (int u = 0; u < 4; ++u) q[u] = qp[u];
}
__device__ __forceinline__ void butterfly_acc(float4 acc[4]) {
#pragma unroll
    for (int u = 0; u < 4; ++u) {
        acc[u].x = rsum_s(acc[u].x);
        acc[u].y = rsum_s(acc[u].y);
        acc[u].z = rsum_s(acc[u].z);
        acc[u].w = rsum_s(acc[u].w);
    }
}

// ===================== Level 0: broadcast layout, 4 q/wave ===================
// Lane = (sq = lane>>4 in 0..3, c = lane&15 owning dims [8c, 8c+8)).
// Wave w: bh = w>>7; g = (w&127)>>1; h = w&1; query i = 8g + 4h + sq.
// Key facts used:
//  * sib keys for query i=8g+sl: rows 8g+j pass iff j<=sl; masked -> row 0.
//  * anc keys: j passes iff j<g — WAVE-UNIFORM; (64-g) masked entries all
//    equal (logit q·K[0], value V[0]) -> handled analytically.
//  * level 0 reads ORIGINAL V everywhere (first level to update).
__global__ __launch_bounds__(256) void level0_kernel(const float* __restrict__ Q,
                                                     const float* __restrict__ K,
                                                     const float* __restrict__ V,
                                                     float* __restrict__ Out) {
    const int w = (blockIdx.x * 256 + threadIdx.x) >> 6;
    const int lane = threadIdx.x & 63;
    const int sq = lane >> 4;       // query slot within wave
    const int c = lane & 15;        // dim chunk (8 floats)
    const int bh = w >> 7;
    const int rem = w & 127;
    const int g = rem >> 1;         // sib group 0..63
    const int h = rem & 1;
    const int sl = 4 * h + sq;      // local query index in group, 0..7
    const int i = 8 * g + sl;       // level-0 query row

    const float* Qb = Q + (size_t)bh * NTOT * D;
    const float* Kb = K + (size_t)bh * NTOT * D;
    const float* Vb = V + (size_t)bh * NTOT * D;
    float* Ob = Out + (size_t)bh * NTOT * D;

    // q chunk: 8 floats
    float4 qa, qb;
    {
        const float4* qp = (const float4*)(Qb + (size_t)i * D + (c << 3));
        qa = qp[0]; qb = qp[1];
    }

    // dot of q-chunk vs row-chunk, reduced over the 16 c-lanes (within sq group)
    auto dot8 = [&](const float* __restrict__ row) -> float {
        const float4* p = (const float4*)(row + (c << 3));
        float4 a = p[0], b = p[1];
        float d = qa.x * a.x + qa.y * a.y + qa.z * a.z + qa.w * a.w
                + qb.x * b.x + qb.y * b.y + qb.z * b.z + qb.w * b.w;
        d += __shfl_xor(d, 1, 64);
        d += __shfl_xor(d, 2, 64);
        d += __shfl_xor(d, 4, 64);
        d += __shfl_xor(d, 8, 64);
        return d * SCALE;
    };

    // masked-entry shared data: K row 0 logit, V row 0 chunk
    const float lg0 = dot8(Kb);
    float4 v0a, v0b;
    {
        const float4* vp = (const float4*)(Vb + (c << 3));
        v0a = vp[0]; v0b = vp[1];
    }

    float4 outA = {0, 0, 0, 0}, outB = {0, 0, 0, 0};

    // ------------------------------- sib ------------------------------------
    {
        float lgs[8];
#pragma unroll
        for (int j = 0; j < 8; ++j) lgs[j] = dot8(Kb + (size_t)(8 * g + j) * D);
        float m = lg0;
#pragma unroll
        for (int j = 0; j < 8; ++j) m = fmaxf(m, lgs[j]);  // upper bound is exact-safe
        const float e0 = __expf(lg0 - m);
        const float w0 = (float)(7 - sl) * e0;
        float z = w0;
        float4 acca = make_float4(w0 * v0a.x, w0 * v0a.y, w0 * v0a.z, w0 * v0a.w);
        float4 accb = make_float4(w0 * v0b.x, w0 * v0b.y, w0 * v0b.z, w0 * v0b.w);
#pragma unroll
        for (int j = 0; j < 8; ++j) {
            const float ej = (j <= sl) ? __expf(lgs[j] - m) : 0.f;
            z += ej;
            const float4* vp = (const float4*)(Vb + (size_t)(8 * g + j) * D + (c << 3));
            float4 va = vp[0], vb2 = vp[1];
            acca.x += ej * va.x;  acca.y += ej * va.y;  acca.z += ej * va.z;  acca.w += ej * va.w;
            accb.x += ej * vb2.x; accb.y += ej * vb2.y; accb.z += ej * vb2.z; accb.w += ej * vb2.w;
        }
        const float inv = 1.f / z;
        outA.x += acca.x * inv; outA.y += acca.y * inv; outA.z += acca.z * inv; outA.w += acca.w * inv;
        outB.x += accb.x * inv; outB.y += accb.y * inv; outB.z += accb.z * inv; outB.w += accb.w * inv;
    }

    // ------------------------------- anc ------------------------------------
    // softmax over: {q·K[512+j] : j<g} ∪ (64-g) copies of lg0 (value V[0]).
    {
        float m_run = lg0;
        float z_run = (float)(64 - g);
        float4 acca = make_float4(z_run * v0a.x, z_run * v0a.y, z_run * v0a.z, z_run * v0a.w);
        float4 accb = make_float4(z_run * v0b.x, z_run * v0b.y, z_run * v0b.z, z_run * v0b.w);
        for (int j0 = 0; j0 < g; j0 += 8) {       // wave-uniform bound
            float lg[8];
#pragma unroll
            for (int t = 0; t < 8; ++t) {
                const int j = j0 + t;
                lg[t] = (j < g) ? dot8(Kb + (size_t)(512 + j) * D) : -1e30f;
            }
            float mb = lg[0];
#pragma unroll
            for (int t = 1; t < 8; ++t) mb = fmaxf(mb, lg[t]);
            const float m_new = fmaxf(m_run, mb);
            const float al = __expf(m_run - m_new);
            z_run *= al;
            acca.x *= al; acca.y *= al; acca.z *= al; acca.w *= al;
            accb.x *= al; accb.y *= al; accb.z *= al; accb.w *= al;
#pragma unroll
            for (int t = 0; t < 8; ++t) {
                const int j = j0 + t;
                if (j < g) {                       // wave-uniform
                    const float e = __expf(lg[t] - m_new);
                    z_run += e;
                    const float4* vp = (const float4*)(Vb + (size_t)(512 + j) * D + (c << 3));
                    float4 va = vp[0], vb2 = vp[1];
                    acca.x += e * va.x;  acca.y += e * va.y;  acca.z += e * va.z;  acca.w += e * va.w;
                    accb.x += e * vb2.x; accb.y += e * vb2.y; accb.z += e * vb2.z; accb.w += e * vb2.w;
                }
            }
            m_run = m_new;
        }
        const float inv = 1.f / z_run;
        outA.x += acca.x * inv; outA.y += acca.y * inv; outA.z += acca.z * inv; outA.w += acca.w * inv;
        outB.x += accb.x * inv; outB.y += accb.y * inv; outB.z += accb.z * inv; outB.w += accb.w * inv;
    }

    // ------------------------------ store ------------------------------------
    float4* op = (float4*)(Ob + (size_t)i * D + (c << 3));
    op[0] = make_float4(outA.x * THIRD, outA.y * THIRD, outA.z * THIRD, outA.w * THIRD);
    op[1] = make_float4(outB.x * THIRD, outB.y * THIRD, outB.z * THIRD, outB.w * THIRD);
}

// ===================== Level 1: R2-proven, 1 query/wave ======================
__global__ __launch_bounds__(256) void level1_kernel(const float* __restrict__ Q,
                                                     const float* __restrict__ K,
                                                     const float* __restrict__ V,
                                                     float* __restrict__ Out) {
    const int gwave = (blockIdx.x * 256 + threadIdx.x) >> 6;
    const int lane = threadIdx.x & 63;
    const int s = lane >> 3, c = lane & 7;
    const int i = gwave & 63;
    const int bh = gwave >> 6;
    const float* Qb = Q + (size_t)bh * NTOT * D;
    const float* Kb = K + (size_t)bh * NTOT * D;
    const float* Vb = V + (size_t)bh * NTOT * D;
    float* Ob = Out + (size_t)bh * NTOT * D;

    float4 q4[4];
    loadq(Qb + (size_t)(512 + i) * D, c, q4);
    float4 acc[4] = {{0,0,0,0},{0,0,0,0},{0,0,0,0},{0,0,0,0}};
    // sib: r<=i -> 512+r (V original); masked -> row 0 (V updated = Out)
    {
        const int r = (i & ~7) + s;
        const bool pass = (r <= i);
        const float* krow = Kb + (size_t)(pass ? 512 + r : 0) * D;
        const float* vrow = pass ? (Vb + (size_t)(512 + r) * D) : Ob;
        attend(q4, krow, vrow, c, acc);
    }
    // anc: 8(s+1)<=i -> 576+s (V original); masked -> row 0 updated
    {
        const bool pass = (8 * (s + 1) <= i);
        const float* krow = Kb + (size_t)(pass ? 576 + s : 0) * D;
        const float* vrow = pass ? (Vb + (size_t)(576 + s) * D) : Ob;
        attend(q4, krow, vrow, c, acc);
    }
    // chi: s==0 -> row 8i (V updated); masked -> row 0 updated
    {
        const int idx = (s == 0) ? 8 * i : 0;
        attend(q4, Kb + (size_t)idx * D, Ob + (size_t)idx * D, c, acc);
    }
    butterfly_acc(acc);
    if (s == 0) {
        float4* orow = (float4*)(Ob + (size_t)(512 + i) * D + (c << 4));
#pragma unroll
        for (int u = 0; u < 4; ++u)
            orow[u] = make_float4(acc[u].x * THIRD, acc[u].y * THIRD,
                                  acc[u].z * THIRD, acc[u].w * THIRD);
    }
}

// ===================== Levels 2+3: R2-proven, 8 blocks =======================
__global__ __launch_bounds__(512) void levels23_kernel(const float* __restrict__ Q,
                                                       const float* __restrict__ K,
                                                       const float* __restrict__ V,
                                                       float* __restrict__ Out) {
    const int bh = blockIdx.x;
    const int wave = threadIdx.x >> 6;
    const int lane = threadIdx.x & 63;
    const int s = lane >> 3, c = lane & 7;
    const float* Qb = Q + (size_t)bh * NTOT * D;
    const float* Kb = K + (size_t)bh * NTOT * D;
    const float* Vb = V + (size_t)bh * NTOT * D;
    float* Ob = Out + (size_t)bh * NTOT * D;

    const int i = wave;  // level-2 query 0..7
    float4 q4[4];
    loadq(Qb + (size_t)(576 + i) * D, c, q4);
    float4 acc[4] = {{0,0,0,0},{0,0,0,0},{0,0,0,0},{0,0,0,0}};
    {
        const bool pass = (s <= i);
        const float* krow = Kb + (size_t)(pass ? 576 + s : 0) * D;
        const float* vrow = pass ? (Vb + (size_t)(576 + s) * D) : Ob;
        attend(q4, krow, vrow, c, acc);
    }
    {
        const int idx = (s == 0) ? (512 + 8 * i) : 0;
        attend(q4, Kb + (size_t)idx * D, Ob + (size_t)idx * D, c, acc);
    }
    butterfly_acc(acc);
    // anc: single always-masked entry -> weight 1 on UPDATED row 0 (post-butterfly)
    float4 o23[4];
    {
        const float4* r0 = (const float4*)(Ob + (c << 4));
#pragma unroll
        for (int u = 0; u < 4; ++u) {
            float4 z = r0[u];
            o23[u] = make_float4((acc[u].x + z.x) * THIRD, (acc[u].y + z.y) * THIRD,
                                 (acc[u].z + z.z) * THIRD, (acc[u].w + z.w) * THIRD);
        }
    }
    if (s == 0) {
        float4* orow = (float4*)(Ob + (size_t)(576 + i) * D + (c << 4));
#pragma unroll
        for (int u = 0; u < 4; ++u) orow[u] = o23[u];
    }
    // ---- level 3 (wave 0): row 584; updated row 576 = o23 in registers ----
    if (wave == 0) {
        float4 q5[4];
        loadq(Qb + (size_t)584 * D, c, q5);
        const float* krow = Kb + (size_t)((s == 0) ? 576 : 0) * D;
        float lg = rsum_c(dot16(q5, krow, c)) * SCALE;
        float m = rmax_s(lg);
        float e = __expf(lg - m);
        float z = rsum_s(e);
        const float w = e / z;
        const float4* r0 = (const float4*)(Ob + (c << 4));
        float4 acc3[4];
#pragma unroll
        for (int u = 0; u < 4; ++u) {
            float4 vv = r0[u];
            if (s == 0) vv = o23[u];
            acc3[u] = make_float4(w * vv.x, w * vv.y, w * vv.z, w * vv.w);
        }
        butterfly_acc(acc3);
        // sib: 8 identical entries on row 584 -> contributes ORIGINAL V[584]
        if (s == 0) {
            const float4* v584 = (const float4*)(Vb + (size_t)584 * D + (c << 4));
            float4* orow = (float4*)(Ob + (size_t)584 * D + (c << 4));
#pragma unroll
            for (int u = 0; u < 4; ++u) {
                float4 bb = v584[u];
                orow[u] = make_float4((acc3[u].x + bb.x) * THIRD, (acc3[u].y + bb.y) * THIRD,
                                      (acc3[u].z + bb.z) * THIRD, (acc3[u].w + bb.w) * THIRD);
            }
        }
    }
}

extern "C" void kernel_launch(void* const* d_in, const int* in_sizes, int n_in,
                              void* d_out, int out_size, void* d_ws, size_t ws_size,
                              hipStream_t stream) {
    const float* Q = (const float*)d_in[0];
    const float* K = (const float*)d_in[1];
    const float* V = (const float*)d_in[2];
    float* Out = (float*)d_out;
    // L0: 1024 waves (8 bh x 64 groups x 2 halves), 4 queries/wave
    hipLaunchKernelGGL(level0_kernel, dim3(256), dim3(256), 0, stream, Q, K, V, Out);
    // L1: 512 waves (8 bh x 64 queries)
    hipLaunchKernelGGL(level1_kernel, dim3(128), dim3(256), 0, stream, Q, K, V, Out);
    // L2+L3: 8 blocks x 8 waves; level 3 chains inside wave 0
    hipLaunchKernelGGL(levels23_kernel, dim3(8), dim3(512), 0, stream, Q, K, V, Out);
}

// Round 6
// 87.969 us; speedup vs baseline: 2.7029x; 1.2667x over previous
//
#include <hip/hip_runtime.h>
#include <math.h>

// Problem constants: b=2, h=4, n_tot=585, d=128, n=512, k=8
// Levels: L0 rows [0,512), L1 [512,576), L2 [576,584), L3 {584}
// Lane layout: s = lane>>3 (key slot 0..7), c = lane&7 (dim chunk of 16)
#define D 128
#define NTOT 585
#define SCALE 0.08838834764831845f  // 1/sqrt(128)
#define THIRD 0.33333333333333333f

__device__ __forceinline__ float rsum_c(float v) {  // sum over c (strides 1,2,4)
    v += __shfl_xor(v, 1, 64);
    v += __shfl_xor(v, 2, 64);
    v += __shfl_xor(v, 4, 64);
    return v;
}
__device__ __forceinline__ float rsum_s(float v) {  // sum over s (strides 8,16,32)
    v += __shfl_xor(v, 8, 64);
    v += __shfl_xor(v, 16, 64);
    v += __shfl_xor(v, 32, 64);
    return v;
}
__device__ __forceinline__ float rmax_s(float v) {
    v = fmaxf(v, __shfl_xor(v, 8, 64));
    v = fmaxf(v, __shfl_xor(v, 16, 64));
    v = fmaxf(v, __shfl_xor(v, 32, 64));
    return v;
}
__device__ __forceinline__ float dot16(const float4 q[4], const float* __restrict__ row, int c) {
    const float4* k = (const float4*)(row + (c << 4));
    float4 k0 = k[0], k1 = k[1], k2 = k[2], k3 = k[3];
    float p0 = q[0].x * k0.x + q[0].y * k0.y + q[0].z * k0.z + q[0].w * k0.w;
    float p1 = q[1].x * k1.x + q[1].y * k1.y + q[1].z * k1.z + q[1].w * k1.w;
    float p2 = q[2].x * k2.x + q[2].y * k2.y + q[2].z * k2.z + q[2].w * k2.w;
    float p3 = q[3].x * k3.x + q[3].y * k3.y + q[3].z * k3.z + q[3].w * k3.w;
    return (p0 + p1) + (p2 + p3);
}
__device__ __forceinline__ void vacc(float w, const float* __restrict__ row, int c, float4 acc[4]) {
    const float4* v = (const float4*)(row + (c << 4));
#pragma unroll
    for (int u = 0; u < 4; ++u) {
        float4 t = v[u];
        acc[u].x += w * t.x; acc[u].y += w * t.y; acc[u].z += w * t.z; acc[u].w += w * t.w;
    }
}
__device__ __forceinline__ void attend(const float4 q[4], const float* __restrict__ krow,
                                       const float* __restrict__ vrow, int c, float4 acc[4]) {
    float lg = rsum_c(dot16(q, krow, c)) * SCALE;
    float m = rmax_s(lg);
    float e = __expf(lg - m);
    float z = rsum_s(e);
    vacc(e / z, vrow, c, acc);
}
__device__ __forceinline__ void loadq(const float* __restrict__ qrow, int c, float4 q[4]) {
    const float4* qp = (const float4*)(qrow + (c << 4));
#pragma unroll
    for (int u = 0; u < 4; ++u) q[u] = qp[u];
}
__device__ __forceinline__ void butterfly_acc(float4 acc[4]) {
#pragma unroll
    for (int u = 0; u < 4; ++u) {
        acc[u].x = rsum_s(acc[u].x);
        acc[u].y = rsum_s(acc[u].y);
        acc[u].z = rsum_s(acc[u].z);
        acc[u].w = rsum_s(acc[u].w);
    }
}

// ================= Level 0: R2-proven, 1 query/wave, 4096 waves ==============
__global__ __launch_bounds__(256) void level0_kernel(const float* __restrict__ Q,
                                                     const float* __restrict__ K,
                                                     const float* __restrict__ V,
                                                     float* __restrict__ Out) {
    const int gwave = (blockIdx.x * 256 + threadIdx.x) >> 6;
    const int lane = threadIdx.x & 63;
    const int s = lane >> 3, c = lane & 7;
    const int i = gwave & 511;
    const int bh = gwave >> 9;
    const float* Qb = Q + (size_t)bh * NTOT * D;
    const float* Kb = K + (size_t)bh * NTOT * D;
    const float* Vb = V + (size_t)bh * NTOT * D;
    float* Ob = Out + (size_t)bh * NTOT * D;

    float4 q4[4];
    loadq(Qb + (size_t)i * D, c, q4);
    float4 acc[4] = {{0,0,0,0},{0,0,0,0},{0,0,0,0},{0,0,0,0}};
    // sib: all original K/V
    {
        const int r = (i & ~7) + s;
        const int idx = (r <= i) ? r : 0;
        attend(q4, Kb + (size_t)idx * D, Vb + (size_t)idx * D, c, acc);
    }
    // anc: 64 entries in 8 parallel slot-rounds, one joint softmax
    {
        float lg[8];
        int idx[8];
#pragma unroll
        for (int r = 0; r < 8; ++r) {
            const int j = 8 * r + s;
            idx[r] = (8 * (j + 1) <= i) ? (512 + j) : 0;
            lg[r] = rsum_c(dot16(q4, Kb + (size_t)idx[r] * D, c)) * SCALE;
        }
        float m = lg[0];
#pragma unroll
        for (int r = 1; r < 8; ++r) m = fmaxf(m, lg[r]);
        m = rmax_s(m);
        float z = 0.f;
#pragma unroll
        for (int r = 0; r < 8; ++r) { lg[r] = __expf(lg[r] - m); z += lg[r]; }
        z = rsum_s(z);
        const float inv = 1.f / z;
#pragma unroll
        for (int r = 0; r < 8; ++r) vacc(lg[r] * inv, Vb + (size_t)idx[r] * D, c, acc);
    }
    butterfly_acc(acc);
    if (s == 0) {
        float4* orow = (float4*)(Ob + (size_t)i * D + (c << 4));
#pragma unroll
        for (int u = 0; u < 4; ++u)
            orow[u] = make_float4(acc[u].x * THIRD, acc[u].y * THIRD,
                                  acc[u].z * THIRD, acc[u].w * THIRD);
    }
}

// ============ Levels 1+2+3 merged: 512 waves, intra-wave chaining ============
// Wave (bh, i): computes L1 query i (row 512+i). If i%8==0, chains L2 query
// j=i/8 (row 576+j) using its own L1 output from registers (chi row 512+8j).
// If i==0, further chains L3 (row 584) using its own L2 output.
// Cross-wave reads are ONLY of L0 outputs (Out rows 0..511, stable from the
// previous launch) and original Q/K/V — no intra-kernel races.
__global__ __launch_bounds__(256) void level123_kernel(const float* __restrict__ Q,
                                                       const float* __restrict__ K,
                                                       const float* __restrict__ V,
                                                       float* __restrict__ Out) {
    const int gwave = (blockIdx.x * 256 + threadIdx.x) >> 6;
    const int lane = threadIdx.x & 63;
    const int s = lane >> 3, c = lane & 7;
    const int i = gwave & 63;
    const int bh = gwave >> 6;
    const float* Qb = Q + (size_t)bh * NTOT * D;
    const float* Kb = K + (size_t)bh * NTOT * D;
    const float* Vb = V + (size_t)bh * NTOT * D;
    float* Ob = Out + (size_t)bh * NTOT * D;

    // ------------------------------ Level 1 ---------------------------------
    float4 o1[4];
    {
        float4 q4[4];
        loadq(Qb + (size_t)(512 + i) * D, c, q4);
        float4 acc[4] = {{0,0,0,0},{0,0,0,0},{0,0,0,0},{0,0,0,0}};
        // sib: r<=i -> 512+r (V original); masked -> row 0 (V updated = Out)
        {
            const int r = (i & ~7) + s;
            const bool pass = (r <= i);
            const float* krow = Kb + (size_t)(pass ? 512 + r : 0) * D;
            const float* vrow = pass ? (Vb + (size_t)(512 + r) * D) : Ob;
            attend(q4, krow, vrow, c, acc);
        }
        // anc: 8(s+1)<=i -> 576+s (V original); masked -> row 0 updated
        {
            const bool pass = (8 * (s + 1) <= i);
            const float* krow = Kb + (size_t)(pass ? 576 + s : 0) * D;
            const float* vrow = pass ? (Vb + (size_t)(576 + s) * D) : Ob;
            attend(q4, krow, vrow, c, acc);
        }
        // chi: s==0 -> row 8i (V updated from L0); masked -> row 0 updated
        {
            const int idx = (s == 0) ? 8 * i : 0;
            attend(q4, Kb + (size_t)idx * D, Ob + (size_t)idx * D, c, acc);
        }
        butterfly_acc(acc);
#pragma unroll
        for (int u = 0; u < 4; ++u)
            o1[u] = make_float4(acc[u].x * THIRD, acc[u].y * THIRD,
                                acc[u].z * THIRD, acc[u].w * THIRD);
        if (s == 0) {
            float4* orow = (float4*)(Ob + (size_t)(512 + i) * D + (c << 4));
#pragma unroll
            for (int u = 0; u < 4; ++u) orow[u] = o1[u];
        }
    }

    // --------------------- Level 2 (waves with i ≡ 0 mod 8) -----------------
    if ((i & 7) == 0) {
        const int j = i >> 3;  // level-2 query 0..7
        const float4* r0 = (const float4*)(Ob + (c << 4));  // updated row 0 chunk
        float4 q2[4];
        loadq(Qb + (size_t)(576 + j) * D, c, q2);
        float4 acc[4] = {{0,0,0,0},{0,0,0,0},{0,0,0,0},{0,0,0,0}};
        // sib: s<=j -> 576+s (V original); masked -> row 0 updated
        {
            const bool pass = (s <= j);
            const float* krow = Kb + (size_t)(pass ? 576 + s : 0) * D;
            const float* vrow = pass ? (Vb + (size_t)(576 + s) * D) : Ob;
            attend(q2, krow, vrow, c, acc);
        }
        // chi: s==0 -> K row 512+8j, V = o1 (this wave's L1 output, registers);
        //      masked -> K row 0, V = updated row 0
        {
            const float* krow = (s == 0) ? (Kb + (size_t)(512 + 8 * j) * D) : Kb;
            float lg = rsum_c(dot16(q2, krow, c)) * SCALE;
            float m = rmax_s(lg);
            float e = __expf(lg - m);
            float z = rsum_s(e);
            const float w = e / z;
#pragma unroll
            for (int u = 0; u < 4; ++u) {
                float4 vv = (s == 0) ? o1[u] : r0[u];
                acc[u].x += w * vv.x; acc[u].y += w * vv.y;
                acc[u].z += w * vv.z; acc[u].w += w * vv.w;
            }
        }
        butterfly_acc(acc);
        // anc: single always-masked entry -> weight exactly 1 on updated row 0
        float4 o2[4];
#pragma unroll
        for (int u = 0; u < 4; ++u) {
            float4 z = r0[u];
            o2[u] = make_float4((acc[u].x + z.x) * THIRD, (acc[u].y + z.y) * THIRD,
                                (acc[u].z + z.z) * THIRD, (acc[u].w + z.w) * THIRD);
        }
        if (s == 0) {
            float4* orow = (float4*)(Ob + (size_t)(576 + j) * D + (c << 4));
#pragma unroll
            for (int u = 0; u < 4; ++u) orow[u] = o2[u];
        }

        // --------------------- Level 3 (wave with i == 0) -------------------
        if (j == 0) {
            float4 q3[4];
            loadq(Qb + (size_t)584 * D, c, q3);
            // chi: s==0 -> K row 576, V = o2 (registers); masked -> K row 0,
            //      V = updated row 0
            const float* krow = (s == 0) ? (Kb + (size_t)576 * D) : Kb;
            float lg = rsum_c(dot16(q3, krow, c)) * SCALE;
            float m = rmax_s(lg);
            float e = __expf(lg - m);
            float z = rsum_s(e);
            const float w = e / z;
            float4 acc3[4];
#pragma unroll
            for (int u = 0; u < 4; ++u) {
                float4 vv = (s == 0) ? o2[u] : r0[u];
                acc3[u] = make_float4(w * vv.x, w * vv.y, w * vv.z, w * vv.w);
            }
            butterfly_acc(acc3);
            // sib: 8 identical entries on row 584 -> contributes ORIGINAL
            // V[584] exactly (weights 1/8 each); add once, post-butterfly.
            if (s == 0) {
                const float4* v584 = (const float4*)(Vb + (size_t)584 * D + (c << 4));
                float4* orow = (float4*)(Ob + (size_t)584 * D + (c << 4));
#pragma unroll
                for (int u = 0; u < 4; ++u) {
                    float4 bb = v584[u];
                    orow[u] = make_float4((acc3[u].x + bb.x) * THIRD,
                                          (acc3[u].y + bb.y) * THIRD,
                                          (acc3[u].z + bb.z) * THIRD,
                                          (acc3[u].w + bb.w) * THIRD);
                }
            }
        }
    }
}

extern "C" void kernel_launch(void* const* d_in, const int* in_sizes, int n_in,
                              void* d_out, int out_size, void* d_ws, size_t ws_size,
                              hipStream_t stream) {
    const float* Q = (const float*)d_in[0];
    const float* K = (const float*)d_in[1];
    const float* V = (const float*)d_in[2];
    float* Out = (float*)d_out;
    // L0: 4096 waves (8 bh x 512 queries), 1 query/wave — max latency hiding
    hipLaunchKernelGGL(level0_kernel, dim3(1024), dim3(256), 0, stream, Q, K, V, Out);
    // L1+L2+L3: 512 waves; L2/L3 chain inside the producing wave (no barriers)
    hipLaunchKernelGGL(level123_kernel, dim3(128), dim3(256), 0, stream, Q, K, V, Out);
}

// Round 7
// 87.803 us; speedup vs baseline: 2.7080x; 1.0019x over previous
//
#include <hip/hip_runtime.h>
#include <math.h>

// Problem constants: b=2, h=4, n_tot=585, d=128, n=512, k=8
// Levels: L0 rows [0,512), L1 [512,576), L2 [576,584), L3 {584}
// Lane layout: s = lane>>3 (key slot 0..7), c = lane&7 (dim chunk of 16)
//
// Dependency closure (lets everything run in ONE kernel, no sync):
//  * updated row 0 = (2/3)*V[0] analytically (L0 query 0: sib and anc both
//    collapse to softmax over identical row-0 entries -> V[0] each).
//  * L1 query i's chi row 8i (an L0 output) is recomputed in-wave —
//    bit-identical code path -> bit-identical value.
//  * L2 query j chains in the wave that computed L1 query 8j (registers).
//  * L3 chains in the wave that computed L2 query 0 (registers).
#define D 128
#define NTOT 585
#define SCALE 0.08838834764831845f  // 1/sqrt(128)
#define THIRD 0.33333333333333333f

__device__ __forceinline__ float rsum_c(float v) {  // sum over c (strides 1,2,4)
    v += __shfl_xor(v, 1, 64);
    v += __shfl_xor(v, 2, 64);
    v += __shfl_xor(v, 4, 64);
    return v;
}
__device__ __forceinline__ float rsum_s(float v) {  // sum over s (strides 8,16,32)
    v += __shfl_xor(v, 8, 64);
    v += __shfl_xor(v, 16, 64);
    v += __shfl_xor(v, 32, 64);
    return v;
}
__device__ __forceinline__ float rmax_s(float v) {
    v = fmaxf(v, __shfl_xor(v, 8, 64));
    v = fmaxf(v, __shfl_xor(v, 16, 64));
    v = fmaxf(v, __shfl_xor(v, 32, 64));
    return v;
}
__device__ __forceinline__ float dot16(const float4 q[4], const float* __restrict__ row, int c) {
    const float4* k = (const float4*)(row + (c << 4));
    float4 k0 = k[0], k1 = k[1], k2 = k[2], k3 = k[3];
    float p0 = q[0].x * k0.x + q[0].y * k0.y + q[0].z * k0.z + q[0].w * k0.w;
    float p1 = q[1].x * k1.x + q[1].y * k1.y + q[1].z * k1.z + q[1].w * k1.w;
    float p2 = q[2].x * k2.x + q[2].y * k2.y + q[2].z * k2.z + q[2].w * k2.w;
    float p3 = q[3].x * k3.x + q[3].y * k3.y + q[3].z * k3.z + q[3].w * k3.w;
    return (p0 + p1) + (p2 + p3);
}
__device__ __forceinline__ void vacc(float w, const float* __restrict__ row, int c, float4 acc[4]) {
    const float4* v = (const float4*)(row + (c << 4));
#pragma unroll
    for (int u = 0; u < 4; ++u) {
        float4 t = v[u];
        acc[u].x += w * t.x; acc[u].y += w * t.y; acc[u].z += w * t.z; acc[u].w += w * t.w;
    }
}
__device__ __forceinline__ void attend(const float4 q[4], const float* __restrict__ krow,
                                       const float* __restrict__ vrow, int c, float4 acc[4]) {
    float lg = rsum_c(dot16(q, krow, c)) * SCALE;
    float m = rmax_s(lg);
    float e = __expf(lg - m);
    float z = rsum_s(e);
    vacc(e / z, vrow, c, acc);
}
// attend with V already materialized in registers (vv selected by caller)
__device__ __forceinline__ void attend_reg(const float4 q[4], const float* __restrict__ krow,
                                           const float4 vv[4], int c, float4 acc[4]) {
    float lg = rsum_c(dot16(q, krow, c)) * SCALE;
    float m = rmax_s(lg);
    float e = __expf(lg - m);
    float z = rsum_s(e);
    const float w = e / z;
#pragma unroll
    for (int u = 0; u < 4; ++u) {
        acc[u].x += w * vv[u].x; acc[u].y += w * vv[u].y;
        acc[u].z += w * vv[u].z; acc[u].w += w * vv[u].w;
    }
}
__device__ __forceinline__ void loadq(const float* __restrict__ qrow, int c, float4 q[4]) {
    const float4* qp = (const float4*)(qrow + (c << 4));
#pragma unroll
    for (int u = 0; u < 4; ++u) q[u] = qp[u];
}
__device__ __forceinline__ void butterfly_acc(float4 acc[4]) {
#pragma unroll
    for (int u = 0; u < 4; ++u) {
        acc[u].x = rsum_s(acc[u].x);
        acc[u].y = rsum_s(acc[u].y);
        acc[u].z = rsum_s(acc[u].z);
        acc[u].w = rsum_s(acc[u].w);
    }
}

// Full L0 query i for slice (Qb,Kb,Vb): returns UNSCALED sib+anc accumulator
// sums on ALL lanes (post-butterfly). R2-proven math.
__device__ __forceinline__ void l0_compute(int i, int s, int c,
                                           const float* __restrict__ Qb,
                                           const float* __restrict__ Kb,
                                           const float* __restrict__ Vb,
                                           float4 acc[4]) {
    float4 q4[4];
    loadq(Qb + (size_t)i * D, c, q4);
#pragma unroll
    for (int u = 0; u < 4; ++u) acc[u] = make_float4(0.f, 0.f, 0.f, 0.f);
    // sib: all original K/V
    {
        const int r = (i & ~7) + s;
        const int idx = (r <= i) ? r : 0;
        attend(q4, Kb + (size_t)idx * D, Vb + (size_t)idx * D, c, acc);
    }
    // anc: 64 entries in 8 parallel slot-rounds, one joint softmax
    {
        float lg[8];
        int idx[8];
#pragma unroll
        for (int r = 0; r < 8; ++r) {
            const int j = 8 * r + s;
            idx[r] = (8 * (j + 1) <= i) ? (512 + j) : 0;
            lg[r] = rsum_c(dot16(q4, Kb + (size_t)idx[r] * D, c)) * SCALE;
        }
        float m = lg[0];
#pragma unroll
        for (int r = 1; r < 8; ++r) m = fmaxf(m, lg[r]);
        m = rmax_s(m);
        float z = 0.f;
#pragma unroll
        for (int r = 0; r < 8; ++r) { lg[r] = __expf(lg[r] - m); z += lg[r]; }
        z = rsum_s(z);
        const float inv = 1.f / z;
#pragma unroll
        for (int r = 0; r < 8; ++r) vacc(lg[r] * inv, Vb + (size_t)idx[r] * D, c, acc);
    }
    butterfly_acc(acc);
}

// ====================== single fused kernel, no synchronization ==============
// Waves [0,4096): L0 queries (bh = w>>9, i = w&511). Write rows [0,512).
// Waves [4096,4608): chain waves (bh = t>>6, i = t&63): recompute L0 row 8i
// in-register, then L1 query i; if i%8==0 chain L2 j=i/8; if i==0 chain L3.
// Write rows [512,585). No wave reads Out — zero cross-wave dependencies.
__global__ __launch_bounds__(256) void sequoia_onepass(const float* __restrict__ Q,
                                                       const float* __restrict__ K,
                                                       const float* __restrict__ V,
                                                       float* __restrict__ Out) {
    const int gwave = (blockIdx.x * 256 + threadIdx.x) >> 6;
    const int lane = threadIdx.x & 63;
    const int s = lane >> 3, c = lane & 7;

    if (gwave < 4096) {
        // ------------------------------ L0 wave ------------------------------
        const int i = gwave & 511;
        const int bh = gwave >> 9;
        const float* Qb = Q + (size_t)bh * NTOT * D;
        const float* Kb = K + (size_t)bh * NTOT * D;
        const float* Vb = V + (size_t)bh * NTOT * D;
        float* Ob = Out + (size_t)bh * NTOT * D;
        float4 acc[4];
        l0_compute(i, s, c, Qb, Kb, Vb, acc);
        if (s == 0) {
            float4* orow = (float4*)(Ob + (size_t)i * D + (c << 4));
#pragma unroll
            for (int u = 0; u < 4; ++u)
                orow[u] = make_float4(acc[u].x * THIRD, acc[u].y * THIRD,
                                      acc[u].z * THIRD, acc[u].w * THIRD);
        }
        return;
    }

    // ------------------------------ chain wave -------------------------------
    const int t = gwave - 4096;
    const int i = t & 63;        // L1 query index 0..63
    const int bh = t >> 6;
    const float* Qb = Q + (size_t)bh * NTOT * D;
    const float* Kb = K + (size_t)bh * NTOT * D;
    const float* Vb = V + (size_t)bh * NTOT * D;
    float* Ob = Out + (size_t)bh * NTOT * D;

    // updated row 0 = (2/3)*V[0] — analytic, no dependency on L0 waves
    float4 v0n[4];
    {
        const float4* vp = (const float4*)(Vb + (c << 4));
#pragma unroll
        for (int u = 0; u < 4; ++u) {
            float4 v = vp[u];
            v0n[u] = make_float4(v.x * (2.f * THIRD), v.y * (2.f * THIRD),
                                 v.z * (2.f * THIRD), v.w * (2.f * THIRD));
        }
    }

    // o0 = updated row 8i (L0 output), recomputed in-wave (bit-identical path)
    float4 o0[4];
    if (i == 0) {
#pragma unroll
        for (int u = 0; u < 4; ++u) o0[u] = v0n[u];
    } else {
        float4 tmp[4];
        l0_compute(8 * i, s, c, Qb, Kb, Vb, tmp);
#pragma unroll
        for (int u = 0; u < 4; ++u)
            o0[u] = make_float4(tmp[u].x * THIRD, tmp[u].y * THIRD,
                                tmp[u].z * THIRD, tmp[u].w * THIRD);
    }

    // ------------------------------- Level 1 ---------------------------------
    float4 o1[4];
    {
        float4 q4[4];
        loadq(Qb + (size_t)(512 + i) * D, c, q4);
        float4 acc[4] = {{0,0,0,0},{0,0,0,0},{0,0,0,0},{0,0,0,0}};
        // sib: r<=i -> K 512+r, V original; masked -> K row 0, V = v0n (regs)
        {
            const int r = (i & ~7) + s;
            const bool pass = (r <= i);
            const float* krow = Kb + (size_t)(pass ? 512 + r : 0) * D;
            float4 vv[4];
            if (pass) {
                const float4* vp = (const float4*)(Vb + (size_t)(512 + r) * D + (c << 4));
#pragma unroll
                for (int u = 0; u < 4; ++u) vv[u] = vp[u];
            } else {
#pragma unroll
                for (int u = 0; u < 4; ++u) vv[u] = v0n[u];
            }
            attend_reg(q4, krow, vv, c, acc);
        }
        // anc: 8(s+1)<=i -> K 576+s, V original; masked -> K row 0, V = v0n
        {
            const bool pass = (8 * (s + 1) <= i);
            const float* krow = Kb + (size_t)(pass ? 576 + s : 0) * D;
            float4 vv[4];
            if (pass) {
                const float4* vp = (const float4*)(Vb + (size_t)(576 + s) * D + (c << 4));
#pragma unroll
                for (int u = 0; u < 4; ++u) vv[u] = vp[u];
            } else {
#pragma unroll
                for (int u = 0; u < 4; ++u) vv[u] = v0n[u];
            }
            attend_reg(q4, krow, vv, c, acc);
        }
        // chi: s==0 -> K row 8i, V = o0 (regs); masked -> K row 0, V = v0n
        {
            const float* krow = (s == 0) ? (Kb + (size_t)(8 * i) * D) : Kb;
            float4 vv[4];
#pragma unroll
            for (int u = 0; u < 4; ++u) vv[u] = (s == 0) ? o0[u] : v0n[u];
            attend_reg(q4, krow, vv, c, acc);
        }
        butterfly_acc(acc);
#pragma unroll
        for (int u = 0; u < 4; ++u)
            o1[u] = make_float4(acc[u].x * THIRD, acc[u].y * THIRD,
                                acc[u].z * THIRD, acc[u].w * THIRD);
        if (s == 0) {
            float4* orow = (float4*)(Ob + (size_t)(512 + i) * D + (c << 4));
#pragma unroll
            for (int u = 0; u < 4; ++u) orow[u] = o1[u];
        }
    }

    // ------------------- Level 2 (waves with i ≡ 0 mod 8) --------------------
    if ((i & 7) == 0) {
        const int j = i >> 3;  // level-2 query 0..7
        float4 q2[4];
        loadq(Qb + (size_t)(576 + j) * D, c, q2);
        float4 acc[4] = {{0,0,0,0},{0,0,0,0},{0,0,0,0},{0,0,0,0}};
        // sib: s<=j -> K 576+s, V original; masked -> K row 0, V = v0n
        {
            const bool pass = (s <= j);
            const float* krow = Kb + (size_t)(pass ? 576 + s : 0) * D;
            float4 vv[4];
            if (pass) {
                const float4* vp = (const float4*)(Vb + (size_t)(576 + s) * D + (c << 4));
#pragma unroll
                for (int u = 0; u < 4; ++u) vv[u] = vp[u];
            } else {
#pragma unroll
                for (int u = 0; u < 4; ++u) vv[u] = v0n[u];
            }
            attend_reg(q2, krow, vv, c, acc);
        }
        // chi: s==0 -> K 512+8j, V = o1 (this wave's L1 output); masked -> row 0 / v0n
        {
            const float* krow = (s == 0) ? (Kb + (size_t)(512 + 8 * j) * D) : Kb;
            float4 vv[4];
#pragma unroll
            for (int u = 0; u < 4; ++u) vv[u] = (s == 0) ? o1[u] : v0n[u];
            attend_reg(q2, krow, vv, c, acc);
        }
        butterfly_acc(acc);
        // anc: single always-masked entry -> weight exactly 1 on updated row 0
        float4 o2[4];
#pragma unroll
        for (int u = 0; u < 4; ++u)
            o2[u] = make_float4((acc[u].x + v0n[u].x) * THIRD, (acc[u].y + v0n[u].y) * THIRD,
                                (acc[u].z + v0n[u].z) * THIRD, (acc[u].w + v0n[u].w) * THIRD);
        if (s == 0) {
            float4* orow = (float4*)(Ob + (size_t)(576 + j) * D + (c << 4));
#pragma unroll
            for (int u = 0; u < 4; ++u) orow[u] = o2[u];
        }

        // ---------------------- Level 3 (wave with i == 0) -------------------
        if (j == 0) {
            float4 q3[4];
            loadq(Qb + (size_t)584 * D, c, q3);
            // chi: s==0 -> K row 576, V = o2 (regs); masked -> K row 0, V = v0n
            const float* krow = (s == 0) ? (Kb + (size_t)576 * D) : Kb;
            float lg = rsum_c(dot16(q3, krow, c)) * SCALE;
            float m = rmax_s(lg);
            float e = __expf(lg - m);
            float z = rsum_s(e);
            const float w = e / z;
            float4 acc3[4];
#pragma unroll
            for (int u = 0; u < 4; ++u) {
                float4 vv = (s == 0) ? o2[u] : v0n[u];
                acc3[u] = make_float4(w * vv.x, w * vv.y, w * vv.z, w * vv.w);
            }
            butterfly_acc(acc3);
            // sib: 8 identical entries on row 584 -> contributes ORIGINAL V[584]
            if (s == 0) {
                const float4* v584 = (const float4*)(Vb + (size_t)584 * D + (c << 4));
                float4* orow = (float4*)(Ob + (size_t)584 * D + (c << 4));
#pragma unroll
                for (int u = 0; u < 4; ++u) {
                    float4 bb = v584[u];
                    orow[u] = make_float4((acc3[u].x + bb.x) * THIRD,
                                          (acc3[u].y + bb.y) * THIRD,
                                          (acc3[u].z + bb.z) * THIRD,
                                          (acc3[u].w + bb.w) * THIRD);
                }
            }
        }
    }
}

extern "C" void kernel_launch(void* const* d_in, const int* in_sizes, int n_in,
                              void* d_out, int out_size, void* d_ws, size_t ws_size,
                              hipStream_t stream) {
    const float* Q = (const float*)d_in[0];
    const float* K = (const float*)d_in[1];
    const float* V = (const float*)d_in[2];
    float* Out = (float*)d_out;
    // 4608 waves total: 4096 L0 + 512 chain waves; 1152 blocks x 4 waves.
    // Single launch, no barriers, no cross-wave reads.
    hipLaunchKernelGGL(sequoia_onepass, dim3(1152), dim3(256), 0, stream, Q, K, V, Out);
}

// Round 8
// 85.287 us; speedup vs baseline: 2.7879x; 1.0295x over previous
//
#include <hip/hip_runtime.h>
#include <math.h>

// Problem constants: b=2, h=4, n_tot=585, d=128, n=512, k=8
// Levels: L0 rows [0,512), L1 [512,576), L2 [576,584), L3 {584}
// Lane layout: s = lane>>3 (key slot 0..7), c = lane&7 (dim chunk of 16)
//
// Masked-entry algebra (exact): every masked selector slot contributes logit
// q.K[0] and value row 0. softmax with cnt identical entries == one term with
// weight cnt*e0. Used to kill all redundant row-0 dots/loads.
// Dependency closure (single kernel, no sync):
//  * updated row 0 = (2/3)*V[0] analytically.
//  * L1 query i's chi row 8i is recomputed in-wave (slim path, fp-equivalent
//    within tolerance).
//  * L2 chains in the wave of L1 query 8j; L3 chains after L2 query 0.
#define D 128
#define NTOT 585
#define SCALE 0.08838834764831845f  // 1/sqrt(128)
#define THIRD 0.33333333333333333f

__device__ __forceinline__ float rsum_c(float v) {  // sum over c (strides 1,2,4)
    v += __shfl_xor(v, 1, 64);
    v += __shfl_xor(v, 2, 64);
    v += __shfl_xor(v, 4, 64);
    return v;
}
__device__ __forceinline__ float rsum_s(float v) {  // sum over s (strides 8,16,32)
    v += __shfl_xor(v, 8, 64);
    v += __shfl_xor(v, 16, 64);
    v += __shfl_xor(v, 32, 64);
    return v;
}
__device__ __forceinline__ float rmax_s(float v) {
    v = fmaxf(v, __shfl_xor(v, 8, 64));
    v = fmaxf(v, __shfl_xor(v, 16, 64));
    v = fmaxf(v, __shfl_xor(v, 32, 64));
    return v;
}
__device__ __forceinline__ float dot16(const float4 q[4], const float* __restrict__ row, int c) {
    const float4* k = (const float4*)(row + (c << 4));
    float4 k0 = k[0], k1 = k[1], k2 = k[2], k3 = k[3];
    float p0 = q[0].x * k0.x + q[0].y * k0.y + q[0].z * k0.z + q[0].w * k0.w;
    float p1 = q[1].x * k1.x + q[1].y * k1.y + q[1].z * k1.z + q[1].w * k1.w;
    float p2 = q[2].x * k2.x + q[2].y * k2.y + q[2].z * k2.z + q[2].w * k2.w;
    float p3 = q[3].x * k3.x + q[3].y * k3.y + q[3].z * k3.z + q[3].w * k3.w;
    return (p0 + p1) + (p2 + p3);
}
__device__ __forceinline__ void vacc(float w, const float* __restrict__ row, int c, float4 acc[4]) {
    const float4* v = (const float4*)(row + (c << 4));
#pragma unroll
    for (int u = 0; u < 4; ++u) {
        float4 t = v[u];
        acc[u].x += w * t.x; acc[u].y += w * t.y; acc[u].z += w * t.z; acc[u].w += w * t.w;
    }
}
__device__ __forceinline__ void vacc_reg(float w, const float4 vv[4], float4 acc[4]) {
#pragma unroll
    for (int u = 0; u < 4; ++u) {
        acc[u].x += w * vv[u].x; acc[u].y += w * vv[u].y;
        acc[u].z += w * vv[u].z; acc[u].w += w * vv[u].w;
    }
}
__device__ __forceinline__ void loadq(const float* __restrict__ qrow, int c, float4 q[4]) {
    const float4* qp = (const float4*)(qrow + (c << 4));
#pragma unroll
    for (int u = 0; u < 4; ++u) q[u] = qp[u];
}
__device__ __forceinline__ void butterfly_acc(float4 acc[4]) {
#pragma unroll
    for (int u = 0; u < 4; ++u) {
        acc[u].x = rsum_s(acc[u].x);
        acc[u].y = rsum_s(acc[u].y);
        acc[u].z = rsum_s(acc[u].z);
        acc[u].w = rsum_s(acc[u].w);
    }
}

// Slim L0 query i: sib+anc with analytic masked entries and wave-uniform anc
// early-exit. Returns UNSCALED (sib+anc) sum on ALL lanes (post-butterfly).
// i must be wave-uniform.
__device__ __forceinline__ void l0_slim(int i, int s, int c,
                                        const float* __restrict__ Qb,
                                        const float* __restrict__ Kb,
                                        const float* __restrict__ Vb,
                                        float4 acc[4]) {
    float4 q4[4];
    loadq(Qb + (size_t)i * D, c, q4);
#pragma unroll
    for (int u = 0; u < 4; ++u) acc[u] = make_float4(0.f, 0.f, 0.f, 0.f);
    const float lg0 = rsum_c(dot16(q4, Kb, c)) * SCALE;  // row-0 logit (shared)
    const int sl = i & 7;   // sib pass slots: s <= sl
    const int g = i >> 3;   // anc pass slots: j < g

    // ------------------------------ sib -------------------------------------
    {
        float lg = -1e30f;
        if (s <= sl)  // uniform within each c-octet -> rsum_c safe
            lg = rsum_c(dot16(q4, Kb + (size_t)(8 * g + s) * D, c)) * SCALE;
        const float m = fmaxf(rmax_s(lg), lg0);
        const float e = (s <= sl) ? __expf(lg - m) : 0.f;
        const float e0 = __expf(lg0 - m);
        float zp = e;
        if (s == 0) zp += (float)(7 - sl) * e0;
        const float inv = 1.f / rsum_s(zp);
        if (s <= sl) vacc(e * inv, Vb + (size_t)(8 * g + s) * D, c, acc);
        if (s == 0 && sl < 7) vacc((float)(7 - sl) * e0 * inv, Vb, c, acc);
    }

    // ------------------------------ anc -------------------------------------
    // softmax over {q.K[512+j] : j<g} ∪ (64-g) copies of lg0 (value V[0]).
    {
        float lgA[8];
        float mloc = lg0;
#pragma unroll
        for (int R = 0; R < 4; ++R) {
            if (16 * R < g) {                       // wave-uniform guard
#pragma unroll
                for (int rr = 0; rr < 2; ++rr) {
                    const int r = 2 * R + rr;
                    const int j = 8 * r + s;
                    float lg = -1e30f;
                    if (j < g)                       // octet-uniform
                        lg = rsum_c(dot16(q4, Kb + (size_t)(512 + j) * D, c)) * SCALE;
                    lgA[r] = lg;
                    mloc = fmaxf(mloc, lg);
                }
            } else { lgA[2 * R] = -1e30f; lgA[2 * R + 1] = -1e30f; }
        }
        const float m = rmax_s(mloc);
        const float e0 = __expf(lg0 - m);
        float zp = (s == 0) ? (float)(64 - g) * e0 : 0.f;
        float eA[8];
#pragma unroll
        for (int R = 0; R < 4; ++R) {
            if (16 * R < g) {
#pragma unroll
                for (int rr = 0; rr < 2; ++rr) {
                    const int r = 2 * R + rr;
                    eA[r] = (lgA[r] > -1e29f) ? __expf(lgA[r] - m) : 0.f;
                    zp += eA[r];
                }
            }
        }
        const float inv = 1.f / rsum_s(zp);
#pragma unroll
        for (int R = 0; R < 4; ++R) {
            if (16 * R < g) {
#pragma unroll
                for (int rr = 0; rr < 2; ++rr) {
                    const int r = 2 * R + rr;
                    const int j = 8 * r + s;
                    if (j < g) vacc(eA[r] * inv, Vb + (size_t)(512 + j) * D, c, acc);
                }
            }
        }
        if (s == 0) vacc((float)(64 - g) * e0 * inv, Vb, c, acc);
    }
    butterfly_acc(acc);
}

// ====================== single fused kernel, no synchronization ==============
// Blocks 0..127 (waves 0..511): chain waves (longest -> dispatched first).
// Blocks 128..1151 (waves 512..4607): L0 queries.
__global__ __launch_bounds__(256) void sequoia_onepass(const float* __restrict__ Q,
                                                       const float* __restrict__ K,
                                                       const float* __restrict__ V,
                                                       float* __restrict__ Out) {
    const int gwave = (blockIdx.x * 256 + threadIdx.x) >> 6;
    const int lane = threadIdx.x & 63;
    const int s = lane >> 3, c = lane & 7;

    if (gwave >= 512) {
        // ------------------------------ L0 wave ------------------------------
        const int w = gwave - 512;
        const int i = w & 511;
        const int bh = w >> 9;
        const float* Qb = Q + (size_t)bh * NTOT * D;
        const float* Kb = K + (size_t)bh * NTOT * D;
        const float* Vb = V + (size_t)bh * NTOT * D;
        float* Ob = Out + (size_t)bh * NTOT * D;
        float4 acc[4];
        l0_slim(i, s, c, Qb, Kb, Vb, acc);
        if (s == 0) {
            float4* orow = (float4*)(Ob + (size_t)i * D + (c << 4));
#pragma unroll
            for (int u = 0; u < 4; ++u)
                orow[u] = make_float4(acc[u].x * THIRD, acc[u].y * THIRD,
                                      acc[u].z * THIRD, acc[u].w * THIRD);
        }
        return;
    }

    // ------------------------------ chain wave -------------------------------
    const int t = gwave;
    const int i = t & 63;        // L1 query index 0..63
    const int bh = t >> 6;
    const float* Qb = Q + (size_t)bh * NTOT * D;
    const float* Kb = K + (size_t)bh * NTOT * D;
    const float* Vb = V + (size_t)bh * NTOT * D;
    float* Ob = Out + (size_t)bh * NTOT * D;

    // updated row 0 = (2/3)*V[0] — analytic
    float4 v0n[4];
    {
        const float4* vp = (const float4*)(Vb + (c << 4));
#pragma unroll
        for (int u = 0; u < 4; ++u) {
            float4 v = vp[u];
            v0n[u] = make_float4(v.x * (2.f * THIRD), v.y * (2.f * THIRD),
                                 v.z * (2.f * THIRD), v.w * (2.f * THIRD));
        }
    }

    // o0 = updated row 8i (L0 output), recomputed in-wave via the slim path
    float4 o0[4];
    if (i == 0) {
#pragma unroll
        for (int u = 0; u < 4; ++u) o0[u] = v0n[u];
    } else {
        float4 tmp[4];
        l0_slim(8 * i, s, c, Qb, Kb, Vb, tmp);
#pragma unroll
        for (int u = 0; u < 4; ++u)
            o0[u] = make_float4(tmp[u].x * THIRD, tmp[u].y * THIRD,
                                tmp[u].z * THIRD, tmp[u].w * THIRD);
    }

    // ------------------------------- Level 1 ---------------------------------
    float4 o1[4];
    {
        float4 q1[4];
        loadq(Qb + (size_t)(512 + i) * D, c, q1);
        float4 acc[4] = {{0,0,0,0},{0,0,0,0},{0,0,0,0},{0,0,0,0}};
        const float lg0q = rsum_c(dot16(q1, Kb, c)) * SCALE;  // row-0 logit
        const int sl1 = i & 7;   // sib pass: s <= sl1
        const int gq = i >> 3;   // anc pass: s < gq
        // sib: pass -> K/V row 512+(i&~7)+s (V original); masked -> (lg0q, v0n)
        {
            const int r = (i & ~7) + s;
            float lg = -1e30f;
            if (s <= sl1)
                lg = rsum_c(dot16(q1, Kb + (size_t)(512 + r) * D, c)) * SCALE;
            const float m = fmaxf(rmax_s(lg), lg0q);
            const float e = (s <= sl1) ? __expf(lg - m) : 0.f;
            const float e0 = __expf(lg0q - m);
            float zp = e;
            if (s == 0) zp += (float)(7 - sl1) * e0;
            const float inv = 1.f / rsum_s(zp);
            if (s <= sl1) vacc(e * inv, Vb + (size_t)(512 + r) * D, c, acc);
            if (s == 0 && sl1 < 7) vacc_reg((float)(7 - sl1) * e0 * inv, v0n, acc);
        }
        // anc: pass -> K/V row 576+s (V original); masked -> (lg0q, v0n)
        {
            float lg = -1e30f;
            if (s < gq)
                lg = rsum_c(dot16(q1, Kb + (size_t)(576 + s) * D, c)) * SCALE;
            const float m = fmaxf(rmax_s(lg), lg0q);
            const float e = (s < gq) ? __expf(lg - m) : 0.f;
            const float e0 = __expf(lg0q - m);
            float zp = e;
            if (s == 0) zp += (float)(8 - gq) * e0;
            const float inv = 1.f / rsum_s(zp);
            if (s < gq) vacc(e * inv, Vb + (size_t)(576 + s) * D, c, acc);
            if (s == 0) vacc_reg((float)(8 - gq) * e0 * inv, v0n, acc);  // gq<=7
        }
        // chi: s==0 -> (K row 8i, o0); 7 masked -> (lg0q, v0n)
        {
            float lg = -1e30f;
            if (s == 0)
                lg = rsum_c(dot16(q1, Kb + (size_t)(8 * i) * D, c)) * SCALE;
            const float m = fmaxf(rmax_s(lg), lg0q);
            const float e = (s == 0) ? __expf(lg - m) : 0.f;
            const float e0 = __expf(lg0q - m);
            const float zp = (s == 0) ? (e + 7.f * e0) : 0.f;
            const float inv = 1.f / rsum_s(zp);
            if (s == 0) {
                vacc_reg(e * inv, o0, acc);
                vacc_reg(7.f * e0 * inv, v0n, acc);
            }
        }
        butterfly_acc(acc);
#pragma unroll
        for (int u = 0; u < 4; ++u)
            o1[u] = make_float4(acc[u].x * THIRD, acc[u].y * THIRD,
                                acc[u].z * THIRD, acc[u].w * THIRD);
        if (s == 0) {
            float4* orow = (float4*)(Ob + (size_t)(512 + i) * D + (c << 4));
#pragma unroll
            for (int u = 0; u < 4; ++u) orow[u] = o1[u];
        }
    }

    // ------------------- Level 2 (waves with i ≡ 0 mod 8) --------------------
    if ((i & 7) == 0) {
        const int j = i >> 3;  // level-2 query 0..7
        float4 q2[4];
        loadq(Qb + (size_t)(576 + j) * D, c, q2);
        float4 acc[4] = {{0,0,0,0},{0,0,0,0},{0,0,0,0},{0,0,0,0}};
        const float lg0q = rsum_c(dot16(q2, Kb, c)) * SCALE;
        // sib: s<=j -> K/V row 576+s (V original); masked -> (lg0q, v0n)
        {
            float lg = -1e30f;
            if (s <= j)
                lg = rsum_c(dot16(q2, Kb + (size_t)(576 + s) * D, c)) * SCALE;
            const float m = fmaxf(rmax_s(lg), lg0q);
            const float e = (s <= j) ? __expf(lg - m) : 0.f;
            const float e0 = __expf(lg0q - m);
            float zp = e;
            if (s == 0) zp += (float)(7 - j) * e0;
            const float inv = 1.f / rsum_s(zp);
            if (s <= j) vacc(e * inv, Vb + (size_t)(576 + s) * D, c, acc);
            if (s == 0 && j < 7) vacc_reg((float)(7 - j) * e0 * inv, v0n, acc);
        }
        // chi: s==0 -> (K row 512+8j, o1); 7 masked -> (lg0q, v0n)
        {
            float lg = -1e30f;
            if (s == 0)
                lg = rsum_c(dot16(q2, Kb + (size_t)(512 + 8 * j) * D, c)) * SCALE;
            const float m = fmaxf(rmax_s(lg), lg0q);
            const float e = (s == 0) ? __expf(lg - m) : 0.f;
            const float e0 = __expf(lg0q - m);
            const float zp = (s == 0) ? (e + 7.f * e0) : 0.f;
            const float inv = 1.f / rsum_s(zp);
            if (s == 0) {
                vacc_reg(e * inv, o1, acc);
                vacc_reg(7.f * e0 * inv, v0n, acc);
            }
        }
        butterfly_acc(acc);
        // anc: single always-masked entry -> weight exactly 1 on updated row 0
        float4 o2[4];
#pragma unroll
        for (int u = 0; u < 4; ++u)
            o2[u] = make_float4((acc[u].x + v0n[u].x) * THIRD, (acc[u].y + v0n[u].y) * THIRD,
                                (acc[u].z + v0n[u].z) * THIRD, (acc[u].w + v0n[u].w) * THIRD);
        if (s == 0) {
            float4* orow = (float4*)(Ob + (size_t)(576 + j) * D + (c << 4));
#pragma unroll
            for (int u = 0; u < 4; ++u) orow[u] = o2[u];
        }

        // ---------------------- Level 3 (wave with i == 0) -------------------
        if (j == 0) {
            float4 q3[4];
            loadq(Qb + (size_t)584 * D, c, q3);
            const float lg0q = rsum_c(dot16(q3, Kb, c)) * SCALE;
            // chi: s==0 -> (K row 576, o2); 7 masked -> (lg0q, v0n)
            float lg = -1e30f;
            if (s == 0)
                lg = rsum_c(dot16(q3, Kb + (size_t)576 * D, c)) * SCALE;
            const float m = fmaxf(rmax_s(lg), lg0q);
            const float e = (s == 0) ? __expf(lg - m) : 0.f;
            const float e0 = __expf(lg0q - m);
            const float zp = (s == 0) ? (e + 7.f * e0) : 0.f;
            const float inv = 1.f / rsum_s(zp);
            float4 acc3[4] = {{0,0,0,0},{0,0,0,0},{0,0,0,0},{0,0,0,0}};
            if (s == 0) {
                vacc_reg(e * inv, o2, acc3);
                vacc_reg(7.f * e0 * inv, v0n, acc3);
            }
            butterfly_acc(acc3);
            // sib: 8 identical entries on row 584 -> contributes ORIGINAL V[584]
            if (s == 0) {
                const float4* v584 = (const float4*)(Vb + (size_t)584 * D + (c << 4));
                float4* orow = (float4*)(Ob + (size_t)584 * D + (c << 4));
#pragma unroll
                for (int u = 0; u < 4; ++u) {
                    float4 bb = v584[u];
                    orow[u] = make_float4((acc3[u].x + bb.x) * THIRD,
                                          (acc3[u].y + bb.y) * THIRD,
                                          (acc3[u].z + bb.z) * THIRD,
                                          (acc3[u].w + bb.w) * THIRD);
                }
            }
        }
    }
}

extern "C" void kernel_launch(void* const* d_in, const int* in_sizes, int n_in,
                              void* d_out, int out_size, void* d_ws, size_t ws_size,
                              hipStream_t stream) {
    const float* Q = (const float*)d_in[0];
    const float* K = (const float*)d_in[1];
    const float* V = (const float*)d_in[2];
    float* Out = (float*)d_out;
    // 4608 waves: 512 chain waves first (longest), then 4096 L0 waves.
    // Single launch, no barriers, no cross-wave reads.
    hipLaunchKernelGGL(sequoia_onepass, dim3(1152), dim3(256), 0, stream, Q, K, V, Out);
}

// Round 9
// 79.503 us; speedup vs baseline: 2.9907x; 1.0728x over previous
//
#include <hip/hip_runtime.h>
#include <math.h>

// Problem constants: b=2, h=4, n_tot=585, d=128, n=512, k=8
// Levels: L0 rows [0,512), L1 [512,576), L2 [576,584), L3 {584}
// Lane layout: s = lane>>3 (key slot 0..7), c = lane&7 (dim chunk of 16)
//
// Masked-entry algebra (exact, R8-proven): every masked selector slot
// contributes logit q.K[0] and value row 0; cnt identical entries == one
// term with weight cnt*e0.  Updated row 0 == (2/3)*V[0].
#define D 128
#define NTOT 585
#define SCALE 0.08838834764831845f  // 1/sqrt(128)
#define THIRD 0.33333333333333333f
#define LROW 132                    // LDS row stride (pad 4): conflict-free b128

__device__ __forceinline__ float rsum_c(float v) {  // sum over c (strides 1,2,4)
    v += __shfl_xor(v, 1, 64);
    v += __shfl_xor(v, 2, 64);
    v += __shfl_xor(v, 4, 64);
    return v;
}
__device__ __forceinline__ float rsum_s(float v) {  // sum over s (strides 8,16,32)
    v += __shfl_xor(v, 8, 64);
    v += __shfl_xor(v, 16, 64);
    v += __shfl_xor(v, 32, 64);
    return v;
}
__device__ __forceinline__ float rmax_s(float v) {
    v = fmaxf(v, __shfl_xor(v, 8, 64));
    v = fmaxf(v, __shfl_xor(v, 16, 64));
    v = fmaxf(v, __shfl_xor(v, 32, 64));
    return v;
}
__device__ __forceinline__ float dot16(const float4 q[4], const float* __restrict__ row, int c) {
    const float4* k = (const float4*)(row + (c << 4));
    float4 k0 = k[0], k1 = k[1], k2 = k[2], k3 = k[3];
    float p0 = q[0].x * k0.x + q[0].y * k0.y + q[0].z * k0.z + q[0].w * k0.w;
    float p1 = q[1].x * k1.x + q[1].y * k1.y + q[1].z * k1.z + q[1].w * k1.w;
    float p2 = q[2].x * k2.x + q[2].y * k2.y + q[2].z * k2.z + q[2].w * k2.w;
    float p3 = q[3].x * k3.x + q[3].y * k3.y + q[3].z * k3.z + q[3].w * k3.w;
    return (p0 + p1) + (p2 + p3);
}
__device__ __forceinline__ void vacc(float w, const float* __restrict__ row, int c, float4 acc[4]) {
    const float4* v = (const float4*)(row + (c << 4));
#pragma unroll
    for (int u = 0; u < 4; ++u) {
        float4 t = v[u];
        acc[u].x += w * t.x; acc[u].y += w * t.y; acc[u].z += w * t.z; acc[u].w += w * t.w;
    }
}
__device__ __forceinline__ void vacc_reg(float w, const float4 vv[4], float4 acc[4]) {
#pragma unroll
    for (int u = 0; u < 4; ++u) {
        acc[u].x += w * vv[u].x; acc[u].y += w * vv[u].y;
        acc[u].z += w * vv[u].z; acc[u].w += w * vv[u].w;
    }
}
__device__ __forceinline__ void loadq(const float* __restrict__ qrow, int c, float4 q[4]) {
    const float4* qp = (const float4*)(qrow + (c << 4));
#pragma unroll
    for (int u = 0; u < 4; ++u) q[u] = qp[u];
}
__device__ __forceinline__ void butterfly_acc(float4 acc[4]) {
#pragma unroll
    for (int u = 0; u < 4; ++u) {
        acc[u].x = rsum_s(acc[u].x);
        acc[u].y = rsum_s(acc[u].y);
        acc[u].z = rsum_s(acc[u].z);
        acc[u].w = rsum_s(acc[u].w);
    }
}

// =============== Kernel A: level 0 with full LDS staging =====================
// Block = 16 consecutive L0 queries of one bh slice. 1024 threads = 16 waves,
// 1 query/wave.  LDS rows: [0,16) sib K/V (global rows qb0..qb0+15),
// [16,80) anc (global 512..575), 80 = row 0.  85.5 KB -> 1 block/CU.
__global__ __launch_bounds__(1024) void level0_lds(const float* __restrict__ Q,
                                                   const float* __restrict__ K,
                                                   const float* __restrict__ V,
                                                   float* __restrict__ Out) {
    __shared__ float Ks[81 * LROW];
    __shared__ float Vs[81 * LROW];
    const int tid = threadIdx.x;
    const int lane = tid & 63;
    const int s = lane >> 3, c = lane & 7;
    const int bh = blockIdx.x >> 5;
    const int qb0 = (blockIdx.x & 31) << 4;  // first query of this block
    const float* Qb = Q + (size_t)bh * NTOT * D;
    const float* Kb = K + (size_t)bh * NTOT * D;
    const float* Vb = V + (size_t)bh * NTOT * D;
    float* Ob = Out + (size_t)bh * NTOT * D;

    // ---- stage 81 K rows + 81 V rows (coalesced float4) ----
    for (int t = tid; t < 81 * 32; t += 1024) {
        const int row = t >> 5, col = (t & 31) << 2;
        const int src = (row < 16) ? (qb0 + row) : ((row < 80) ? (512 + row - 16) : 0);
        *(float4*)(&Ks[row * LROW + col]) = *(const float4*)(Kb + (size_t)src * D + col);
        *(float4*)(&Vs[row * LROW + col]) = *(const float4*)(Vb + (size_t)src * D + col);
    }
    __syncthreads();

    const int w = tid >> 6;       // wave 0..15
    const int i = qb0 + w;        // this wave's query
    const int sl = i & 7;         // sib pass slots: s <= sl
    const int g = i >> 3;         // anc pass slots: j < g
    const int sibbase = w & 8;    // LDS sib row base for this wave's group

    float4 q4[4];
    loadq(Qb + (size_t)i * D, c, q4);
    float4 acc[4] = {{0,0,0,0},{0,0,0,0},{0,0,0,0},{0,0,0,0}};
    const float lg0 = rsum_c(dot16(q4, &Ks[80 * LROW], c)) * SCALE;

    // ------------------------------ sib -------------------------------------
    {
        float lg = -1e30f;
        if (s <= sl)
            lg = rsum_c(dot16(q4, &Ks[(sibbase + s) * LROW], c)) * SCALE;
        const float m = fmaxf(rmax_s(lg), lg0);
        const float e = (s <= sl) ? __expf(lg - m) : 0.f;
        const float e0 = __expf(lg0 - m);
        float zp = e;
        if (s == 0) zp += (float)(7 - sl) * e0;
        const float inv = 1.f / rsum_s(zp);
        if (s <= sl) vacc(e * inv, &Vs[(sibbase + s) * LROW], c, acc);
        if (s == 0 && sl < 7) vacc((float)(7 - sl) * e0 * inv, &Vs[80 * LROW], c, acc);
    }

    // ------------------------------ anc -------------------------------------
    // softmax over {q.K[512+j] : j<g} ∪ (64-g) copies of lg0 (value V[0]).
    {
        float lgA[8];
        float mloc = lg0;
#pragma unroll
        for (int R = 0; R < 4; ++R) {
            if (16 * R < g) {                       // wave-uniform guard
#pragma unroll
                for (int rr = 0; rr < 2; ++rr) {
                    const int r = 2 * R + rr;
                    const int j = 8 * r + s;
                    float lg = -1e30f;
                    if (j < g)                       // octet-uniform
                        lg = rsum_c(dot16(q4, &Ks[(16 + j) * LROW], c)) * SCALE;
                    lgA[r] = lg;
                    mloc = fmaxf(mloc, lg);
                }
            } else { lgA[2 * R] = -1e30f; lgA[2 * R + 1] = -1e30f; }
        }
        const float m = rmax_s(mloc);
        const float e0 = __expf(lg0 - m);
        float zp = (s == 0) ? (float)(64 - g) * e0 : 0.f;
        float eA[8];
#pragma unroll
        for (int R = 0; R < 4; ++R) {
            if (16 * R < g) {
#pragma unroll
                for (int rr = 0; rr < 2; ++rr) {
                    const int r = 2 * R + rr;
                    eA[r] = (lgA[r] > -1e29f) ? __expf(lgA[r] - m) : 0.f;
                    zp += eA[r];
                }
            }
        }
        const float inv = 1.f / rsum_s(zp);
#pragma unroll
        for (int R = 0; R < 4; ++R) {
            if (16 * R < g) {
#pragma unroll
                for (int rr = 0; rr < 2; ++rr) {
                    const int r = 2 * R + rr;
                    const int j = 8 * r + s;
                    if (j < g) vacc(eA[r] * inv, &Vs[(16 + j) * LROW], c, acc);
                }
            }
        }
        if (s == 0) vacc((float)(64 - g) * e0 * inv, &Vs[80 * LROW], c, acc);
    }
    butterfly_acc(acc);
    if (s == 0) {
        float4* orow = (float4*)(Ob + (size_t)i * D + (c << 4));
#pragma unroll
        for (int u = 0; u < 4; ++u)
            orow[u] = make_float4(acc[u].x * THIRD, acc[u].y * THIRD,
                                  acc[u].z * THIRD, acc[u].w * THIRD);
    }
}

// ============ Kernel B: levels 1+2+3, 512 short waves (reads Out) ============
// Wave (bh,i): L1 query i; o0 = Out row 8i (from kernel A — 1 row read, no
// recompute); v0n = Out row 0 (== (2/3)V[0]).  i%8==0 chains L2 j=i/8 from
// registers; i==0 further chains L3.  R8-proven slim math.
__global__ __launch_bounds__(256) void level123_kernel(const float* __restrict__ Q,
                                                       const float* __restrict__ K,
                                                       const float* __restrict__ V,
                                                       float* __restrict__ Out) {
    const int gwave = (blockIdx.x * 256 + threadIdx.x) >> 6;
    const int lane = threadIdx.x & 63;
    const int s = lane >> 3, c = lane & 7;
    const int i = gwave & 63;
    const int bh = gwave >> 6;
    const float* Qb = Q + (size_t)bh * NTOT * D;
    const float* Kb = K + (size_t)bh * NTOT * D;
    const float* Vb = V + (size_t)bh * NTOT * D;
    float* Ob = Out + (size_t)bh * NTOT * D;

    // v0n = updated row 0; o0 = updated row 8i (both kernel-A outputs)
    float4 v0n[4], o0[4];
    {
        const float4* vp = (const float4*)(Ob + (c << 4));
        const float4* op = (const float4*)(Ob + (size_t)(8 * i) * D + (c << 4));
#pragma unroll
        for (int u = 0; u < 4; ++u) { v0n[u] = vp[u]; o0[u] = op[u]; }
    }

    // ------------------------------- Level 1 ---------------------------------
    float4 o1[4];
    {
        float4 q1[4];
        loadq(Qb + (size_t)(512 + i) * D, c, q1);
        float4 acc[4] = {{0,0,0,0},{0,0,0,0},{0,0,0,0},{0,0,0,0}};
        const float lg0q = rsum_c(dot16(q1, Kb, c)) * SCALE;
        const int sl1 = i & 7;
        const int gq = i >> 3;
        // sib: s<=sl1 -> K/V row 512+(i&~7)+s (V original); masked -> (lg0q, v0n)
        {
            const int r = (i & ~7) + s;
            float lg = -1e30f;
            if (s <= sl1)
                lg = rsum_c(dot16(q1, Kb + (size_t)(512 + r) * D, c)) * SCALE;
            const float m = fmaxf(rmax_s(lg), lg0q);
            const float e = (s <= sl1) ? __expf(lg - m) : 0.f;
            const float e0 = __expf(lg0q - m);
            float zp = e;
            if (s == 0) zp += (float)(7 - sl1) * e0;
            const float inv = 1.f / rsum_s(zp);
            if (s <= sl1) vacc(e * inv, Vb + (size_t)(512 + r) * D, c, acc);
            if (s == 0 && sl1 < 7) vacc_reg((float)(7 - sl1) * e0 * inv, v0n, acc);
        }
        // anc: s<gq -> K/V row 576+s (V original); masked -> (lg0q, v0n)
        {
            float lg = -1e30f;
            if (s < gq)
                lg = rsum_c(dot16(q1, Kb + (size_t)(576 + s) * D, c)) * SCALE;
            const float m = fmaxf(rmax_s(lg), lg0q);
            const float e = (s < gq) ? __expf(lg - m) : 0.f;
            const float e0 = __expf(lg0q - m);
            float zp = e;
            if (s == 0) zp += (float)(8 - gq) * e0;
            const float inv = 1.f / rsum_s(zp);
            if (s < gq) vacc(e * inv, Vb + (size_t)(576 + s) * D, c, acc);
            if (s == 0) vacc_reg((float)(8 - gq) * e0 * inv, v0n, acc);  // gq<=7
        }
        // chi: s==0 -> (K row 8i, o0); 7 masked -> (lg0q, v0n)
        {
            float lg = -1e30f;
            if (s == 0)
                lg = rsum_c(dot16(q1, Kb + (size_t)(8 * i) * D, c)) * SCALE;
            const float m = fmaxf(rmax_s(lg), lg0q);
            const float e = (s == 0) ? __expf(lg - m) : 0.f;
            const float e0 = __expf(lg0q - m);
            const float zp = (s == 0) ? (e + 7.f * e0) : 0.f;
            const float inv = 1.f / rsum_s(zp);
            if (s == 0) {
                vacc_reg(e * inv, o0, acc);
                vacc_reg(7.f * e0 * inv, v0n, acc);
            }
        }
        butterfly_acc(acc);
#pragma unroll
        for (int u = 0; u < 4; ++u)
            o1[u] = make_float4(acc[u].x * THIRD, acc[u].y * THIRD,
                                acc[u].z * THIRD, acc[u].w * THIRD);
        if (s == 0) {
            float4* orow = (float4*)(Ob + (size_t)(512 + i) * D + (c << 4));
#pragma unroll
            for (int u = 0; u < 4; ++u) orow[u] = o1[u];
        }
    }

    // ------------------- Level 2 (waves with i ≡ 0 mod 8) --------------------
    if ((i & 7) == 0) {
        const int j = i >> 3;
        float4 q2[4];
        loadq(Qb + (size_t)(576 + j) * D, c, q2);
        float4 acc[4] = {{0,0,0,0},{0,0,0,0},{0,0,0,0},{0,0,0,0}};
        const float lg0q = rsum_c(dot16(q2, Kb, c)) * SCALE;
        // sib: s<=j -> K/V row 576+s (V original); masked -> (lg0q, v0n)
        {
            float lg = -1e30f;
            if (s <= j)
                lg = rsum_c(dot16(q2, Kb + (size_t)(576 + s) * D, c)) * SCALE;
            const float m = fmaxf(rmax_s(lg), lg0q);
            const float e = (s <= j) ? __expf(lg - m) : 0.f;
            const float e0 = __expf(lg0q - m);
            float zp = e;
            if (s == 0) zp += (float)(7 - j) * e0;
            const float inv = 1.f / rsum_s(zp);
            if (s <= j) vacc(e * inv, Vb + (size_t)(576 + s) * D, c, acc);
            if (s == 0 && j < 7) vacc_reg((float)(7 - j) * e0 * inv, v0n, acc);
        }
        // chi: s==0 -> (K row 512+8j, o1); 7 masked -> (lg0q, v0n)
        {
            float lg = -1e30f;
            if (s == 0)
                lg = rsum_c(dot16(q2, Kb + (size_t)(512 + 8 * j) * D, c)) * SCALE;
            const float m = fmaxf(rmax_s(lg), lg0q);
            const float e = (s == 0) ? __expf(lg - m) : 0.f;
            const float e0 = __expf(lg0q - m);
            const float zp = (s == 0) ? (e + 7.f * e0) : 0.f;
            const float inv = 1.f / rsum_s(zp);
            if (s == 0) {
                vacc_reg(e * inv, o1, acc);
                vacc_reg(7.f * e0 * inv, v0n, acc);
            }
        }
        butterfly_acc(acc);
        // anc: single always-masked entry -> weight exactly 1 on updated row 0
        float4 o2[4];
#pragma unroll
        for (int u = 0; u < 4; ++u)
            o2[u] = make_float4((acc[u].x + v0n[u].x) * THIRD, (acc[u].y + v0n[u].y) * THIRD,
                                (acc[u].z + v0n[u].z) * THIRD, (acc[u].w + v0n[u].w) * THIRD);
        if (s == 0) {
            float4* orow = (float4*)(Ob + (size_t)(576 + j) * D + (c << 4));
#pragma unroll
            for (int u = 0; u < 4; ++u) orow[u] = o2[u];
        }

        // ---------------------- Level 3 (wave with i == 0) -------------------
        if (j == 0) {
            float4 q3[4];
            loadq(Qb + (size_t)584 * D, c, q3);
            const float lg0r = rsum_c(dot16(q3, Kb, c)) * SCALE;
            // chi: s==0 -> (K row 576, o2); 7 masked -> (lg0r, v0n)
            float lg = -1e30f;
            if (s == 0)
                lg = rsum_c(dot16(q3, Kb + (size_t)576 * D, c)) * SCALE;
            const float m = fmaxf(rmax_s(lg), lg0r);
            const float e = (s == 0) ? __expf(lg - m) : 0.f;
            const float e0 = __expf(lg0r - m);
            const float zp = (s == 0) ? (e + 7.f * e0) : 0.f;
            const float inv = 1.f / rsum_s(zp);
            float4 acc3[4] = {{0,0,0,0},{0,0,0,0},{0,0,0,0},{0,0,0,0}};
            if (s == 0) {
                vacc_reg(e * inv, o2, acc3);
                vacc_reg(7.f * e0 * inv, v0n, acc3);
            }
            butterfly_acc(acc3);
            // sib: 8 identical entries on row 584 -> contributes ORIGINAL V[584]
            if (s == 0) {
                const float4* v584 = (const float4*)(Vb + (size_t)584 * D + (c << 4));
                float4* orow = (float4*)(Ob + (size_t)584 * D + (c << 4));
#pragma unroll
                for (int u = 0; u < 4; ++u) {
                    float4 bb = v584[u];
                    orow[u] = make_float4((acc3[u].x + bb.x) * THIRD,
                                          (acc3[u].y + bb.y) * THIRD,
                                          (acc3[u].z + bb.z) * THIRD,
                                          (acc3[u].w + bb.w) * THIRD);
                }
            }
        }
    }
}

extern "C" void kernel_launch(void* const* d_in, const int* in_sizes, int n_in,
                              void* d_out, int out_size, void* d_ws, size_t ws_size,
                              hipStream_t stream) {
    const float* Q = (const float*)d_in[0];
    const float* K = (const float*)d_in[1];
    const float* V = (const float*)d_in[2];
    float* Out = (float*)d_out;
    // A: 256 blocks x 1024 threads (8 bh x 32 blocks of 16 queries), LDS-staged
    hipLaunchKernelGGL(level0_lds, dim3(256), dim3(1024), 0, stream, Q, K, V, Out);
    // B: 512 short waves; reads kernel-A outputs from Out (rows 0, 8i)
    hipLaunchKernelGGL(level123_kernel, dim3(128), dim3(256), 0, stream, Q, K, V, Out);
}